// Round 10
// baseline (232.595 us; speedup 1.0000x reference)
//
#include <hip/hip_runtime.h>
#include <stdint.h>

typedef __attribute__((ext_vector_type(4))) float f32x4;
typedef __attribute__((ext_vector_type(8))) __bf16 bf16x8;
typedef __attribute__((ext_vector_type(8))) unsigned short u16x8;
typedef __attribute__((ext_vector_type(4))) unsigned short u16x4;

__device__ __forceinline__ unsigned short f2b(float f) {
  unsigned u = __float_as_uint(f);
  u += 0x7FFFu + ((u >> 16) & 1u);   // RNE
  return (unsigned short)(u >> 16);
}
__device__ __forceinline__ float b2f(unsigned short s) {
  unsigned u = (unsigned)s << 16;
  return __uint_as_float(u);
}
__device__ __forceinline__ unsigned cvtpk_bf16(float lo, float hi) {
  unsigned r;
  asm("v_cvt_pk_bf16_f32 %0, %1, %2" : "=v"(r) : "v"(lo), "v"(hi));
  return r;
}

__device__ __forceinline__ void gload_lds16(const void* g, void* l) {
  typedef __attribute__((address_space(1))) void GV1;
  typedef __attribute__((address_space(3))) void LV3;
  __builtin_amdgcn_global_load_lds((GV1*)(void*)g, (LV3*)l, 16, 0, 0);
}

// ---------------- conversion kernels ----------------
__global__ __launch_bounds__(256) void convert_f32_bf16(const float* __restrict__ in,
                                                        unsigned short* __restrict__ out, int n) {
  int i = (blockIdx.x * 256 + threadIdx.x) * 8;
  if (i >= n) return;
  float4 a = *(const float4*)(in + i);
  float4 b = *(const float4*)(in + i + 4);
  u16x8 r;
  r[0] = f2b(a.x); r[1] = f2b(a.y); r[2] = f2b(a.z); r[3] = f2b(a.w);
  r[4] = f2b(b.x); r[5] = f2b(b.y); r[6] = f2b(b.z); r[7] = f2b(b.w);
  *(u16x8*)(out + i) = r;
}

// W [K][N] f32 -> Wt [N][K] bf16
__global__ __launch_bounds__(256) void transpose_f32_bf16(const float* __restrict__ W,
                                                          unsigned short* __restrict__ Wt,
                                                          int K, int N) {
  __shared__ unsigned short tile[32][33];
  int n0 = blockIdx.x * 32, k0 = blockIdx.y * 32;
  int tx = threadIdx.x, ty = threadIdx.y;  // 32 x 8
  #pragma unroll
  for (int j = 0; j < 32; j += 8)
    tile[ty + j][tx] = f2b(W[(size_t)(k0 + ty + j) * N + n0 + tx]);
  __syncthreads();
  #pragma unroll
  for (int j = 0; j < 32; j += 8)
    Wt[(size_t)(n0 + ty + j) * K + k0 + tx] = tile[tx][ty + j];
}

// ---------------- GEMM: C[M][N] = A[M][K] * Bt[N][K]^T + bias ----------------
template <bool OUT_BF16>
__global__ __launch_bounds__(256) void gemm_bt(const unsigned short* __restrict__ A,
                                               const unsigned short* __restrict__ Bt,
                                               const float* __restrict__ bias,
                                               void* __restrict__ Cout,
                                               int M, int N, int K) {
  __shared__ unsigned short As[128 * 64];
  __shared__ unsigned short Bs[128 * 64];
  const int m0 = blockIdx.x * 128, n0 = blockIdx.y * 128;
  const int tid = threadIdx.x;
  const int w = tid >> 6, l = tid & 63;
  const int wm = w >> 1, wn = w & 1;
  const int c = l & 15, g = l >> 4;
  f32x4 acc[4][4] = {};
  for (int k0 = 0; k0 < K; k0 += 64) {
    #pragma unroll
    for (int i = 0; i < 4; ++i) {
      int rb = w * 32 + i * 8;
      gload_lds16(A + (size_t)(m0 + rb + (l >> 3)) * K + k0 + (l & 7) * 8, &As[rb * 64]);
      gload_lds16(Bt + (size_t)(n0 + rb + (l >> 3)) * K + k0 + (l & 7) * 8, &Bs[rb * 64]);
    }
    __syncthreads();
    #pragma unroll
    for (int ks = 0; ks < 2; ++ks) {
      bf16x8 af[4], bf[4];
      #pragma unroll
      for (int mi = 0; mi < 4; ++mi)
        af[mi] = *(const bf16x8*)&As[(wm * 64 + mi * 16 + c) * 64 + ks * 32 + g * 8];
      #pragma unroll
      for (int ni = 0; ni < 4; ++ni)
        bf[ni] = *(const bf16x8*)&Bs[(wn * 64 + ni * 16 + c) * 64 + ks * 32 + g * 8];
      #pragma unroll
      for (int mi = 0; mi < 4; ++mi)
        #pragma unroll
        for (int ni = 0; ni < 4; ++ni)
          acc[mi][ni] = __builtin_amdgcn_mfma_f32_16x16x32_bf16(af[mi], bf[ni], acc[mi][ni], 0, 0, 0);
    }
    __syncthreads();
  }
  #pragma unroll
  for (int mi = 0; mi < 4; ++mi) {
    #pragma unroll
    for (int ni = 0; ni < 4; ++ni) {
      int colg = n0 + wn * 64 + ni * 16 + c;
      float bv = bias[colg];
      #pragma unroll
      for (int r = 0; r < 4; ++r) {
        int rowg = m0 + wm * 64 + mi * 16 + 4 * g + r;
        float v = acc[mi][ni][r] + bv;
        if (OUT_BF16)
          ((unsigned short*)Cout)[(size_t)rowg * N + colg] = f2b(v);
        else
          ((float*)Cout)[(size_t)rowg * N + colg] = v;
      }
    }
  }
}

// ---------------- causal flash attention, SPLIT-KV + SWAPPED MFMA, QBLK=128 ----
// qkv [4096][3072] bf16. Block = one 128-row q-tile x one KV chunk of <=8 tiles.
// 8 waves x 16 q-rows, 512 threads, SAME 32KB K/V LDS as R7 -> waves per
// LDS-byte doubled; __launch_bounds__(512,8) forces VGPR<=64 -> 4 blocks/CU =
// 32 waves = 100% wave cap (R9 hypothesis: occupancy ~8 waves/CU was the limit;
// VGPR=68 capped at 16 waves/CU per the 64-VGPR boundary).
// K/V staged once per 128 q (halves staging + L2 traffic). Swapped-MFMA inner
// loop unchanged from R7. Causal mask now per-wave on any tile with
// kv0+63 > q0w; waves fully below diagonal skip compute (wave-uniform).
// Chunk map per bh (40 chunks): qt 0-3 -> 1 chunk; 4-7 -> 2; 8-11 -> 3; 12-15 -> 4.
__global__ __launch_bounds__(512, 8) void attn_kernel(const unsigned short* __restrict__ qkv,
                                                      unsigned short* __restrict__ partO,
                                                      float* __restrict__ partML) {
  __shared__ unsigned short K_lds[2][64 * 64];     // [kv][d], XOR-swizzled rows
  __shared__ unsigned short V_lds[2][64 * 64];     // V^T [d][kv], XOR-swizzled rows
  const int bid = blockIdx.x;
  const int bh = bid & 31;
  const int cid = bid >> 5;                        // 0..39
  int qt, ct;
  if (cid < 4)       { qt = cid;            ct = 0; }
  else if (cid < 12) { int e = cid - 4;  qt = 4 + (e >> 1);  ct = e & 1; }
  else if (cid < 24) { int e = cid - 12; int q3 = e / 3; qt = 8 + q3; ct = e - 3 * q3; }
  else               { int e = cid - 24; qt = 12 + (e >> 2); ct = e & 3; }
  const int ntt = 2 * qt + 2;                      // total kv tiles for this q-tile
  const int t0 = ct * 8;
  const int ntl = min(ntt - t0, 8);                // tiles in this chunk (1..8)
  const int b = bh >> 4, h = bh & 15;
  const int tid = threadIdx.x, w = tid >> 6, l = tid & 63;
  const int c = l & 15, g = l >> 4;
  const int hi = g >> 1;
  const int srcA = c + ((g & 1) << 5);             // bpermute pattern A (j=0,1)
  const int srcB = srcA + 16;                      // pattern B (j=2,3)
  const size_t row0 = (size_t)b * 2048;
  const int vp = tid & 31, vcb = tid >> 5;         // V-stage: kv-pair, d-quad (0..15)
  const float SCL = 0.18033688f;                   // 0.125 * log2(e)

  const int q0w = qt * 128 + w * 16;
  const int qg = q0w + c;                          // this lane's q row (global)

  // Q fragments (B operand of swapped QK^T)
  bf16x8 qf[2];
  #pragma unroll
  for (int ks = 0; ks < 2; ++ks)
    qf[ks] = *(const bf16x8*)(qkv + (row0 + qg) * 3072 + h * 64 + ks * 32 + g * 8);

  f32x4 acc[4] = {};                               // O^T: acc[nd][r] = O[q=c][d=16nd+4g+r]
  float mstate = -1e30f, lstate = 0.f;

  // ---- prologue: stage kv-tile t0 into buffer 0
  {
    int rb = w * 8;                                // 8 waves x 8 rows = 64 kv
    int row = rb + (l >> 3);
    int ch = (l & 7) ^ (row & 7);                  // pre-swizzled source (m173)
    gload_lds16(qkv + (row0 + t0 * 64 + row) * 3072 + 1024 + h * 64 + ch * 8,
                &K_lds[0][rb * 64]);
    size_t tr = row0 + t0 * 64 + 2 * vp;
    u16x4 v0 = *(const u16x4*)(qkv + tr * 3072 + 2048 + h * 64 + vcb * 4);
    u16x4 v1 = *(const u16x4*)(qkv + (tr + 1) * 3072 + 2048 + h * 64 + vcb * 4);
    char* Vb = (char*)V_lds[0];
    #pragma unroll
    for (int jj = 0; jj < 4; ++jj) {
      int d = vcb * 4 + jj;
      int off = d * 128 + ((4 * vp) ^ ((d & 7) << 4));
      *(unsigned int*)(Vb + off) = (unsigned int)v0[jj] | ((unsigned int)v1[jj] << 16);
    }
  }
  __syncthreads();

  for (int lt = 0; lt < ntl; ++lt) {
    const int cur = lt & 1;
    const int kv0 = (t0 + lt) * 64;
    const bool pre = (lt + 1 < ntl);
    u16x4 v0n, v1n;
    if (pre) {  // issue next-tile loads BEFORE compute (2-phase pipeline)
      const int kvn = kv0 + 64;
      int rb = w * 8;
      int row = rb + (l >> 3);
      int ch = (l & 7) ^ (row & 7);
      gload_lds16(qkv + (row0 + kvn + row) * 3072 + 1024 + h * 64 + ch * 8,
                  &K_lds[cur ^ 1][rb * 64]);
      size_t tr = row0 + kvn + 2 * vp;
      v0n = *(const u16x4*)(qkv + tr * 3072 + 2048 + h * 64 + vcb * 4);
      v1n = *(const u16x4*)(qkv + (tr + 1) * 3072 + 2048 + h * 64 + vcb * 4);
    }
    if (kv0 <= q0w + 15) {  // wave-uniform: skip tiles fully above the diagonal
      const char* Kb = (const char*)K_lds[cur];
      const char* Vb = (const char*)V_lds[cur];
      // ---- S^T = mfma(K, Q): s[nk][r] = S[q=qg][kv = kv0 + 16nk + 4g + r]
      f32x4 s[4] = {};
      #pragma unroll
      for (int ks = 0; ks < 2; ++ks) {
        bf16x8 kf[4];
        #pragma unroll
        for (int nk = 0; nk < 4; ++nk) {
          int row = nk * 16 + c;
          kf[nk] = *(const bf16x8*)(Kb + row * 128 + ((ks * 64 + g * 16) ^ ((row & 7) << 4)));
        }
        __builtin_amdgcn_s_setprio(1);
        #pragma unroll
        for (int nk = 0; nk < 4; ++nk)
          s[nk] = __builtin_amdgcn_mfma_f32_16x16x32_bf16(kf[nk], qf[ks], s[nk], 0, 0, 0);
        __builtin_amdgcn_s_setprio(0);
      }
      // ---- causal mask on any tile straddling this wave's rows (wave-uniform)
      if (kv0 + 63 > q0w) {
        #pragma unroll
        for (int nk = 0; nk < 4; ++nk)
          #pragma unroll
          for (int r = 0; r < 4; ++r) {
            int kvg = kv0 + nk * 16 + 4 * g + r;
            if (kvg > qg) s[nk][r] = -1e30f;
          }
      }
      // ---- row max: in-lane tree + 2 shfls (lanes c,c+16,c+32,c+48 share q)
      float a0 = fmaxf(fmaxf(s[0][0], s[0][1]), fmaxf(s[0][2], s[0][3]));
      float a1 = fmaxf(fmaxf(s[1][0], s[1][1]), fmaxf(s[1][2], s[1][3]));
      float a2 = fmaxf(fmaxf(s[2][0], s[2][1]), fmaxf(s[2][2], s[2][3]));
      float a3 = fmaxf(fmaxf(s[3][0], s[3][1]), fmaxf(s[3][2], s[3][3]));
      float mx = fmaxf(fmaxf(a0, a1), fmaxf(a2, a3));
      mx = fmaxf(mx, __shfl_xor(mx, 16));
      mx = fmaxf(mx, __shfl_xor(mx, 32));
      // ---- alpha==1 fast path (wave-uniform); rescale lane-local
      if (!__all(mx <= mstate)) {
        float mnew = fmaxf(mstate, mx);
        float alpha = exp2f((mstate - mnew) * SCL);
        mstate = mnew;
        lstate *= alpha;
        #pragma unroll
        for (int nd = 0; nd < 4; ++nd) acc[nd] *= alpha;
      }
      // ---- P = exp2(s*SCL - m*SCL), per-lane l partial
      float ms = mstate * SCL;
      #pragma unroll
      for (int nk = 0; nk < 4; ++nk) {
        #pragma unroll
        for (int r = 0; r < 4; ++r) s[nk][r] = exp2f(fmaf(s[nk][r], SCL, -ms));
        lstate += (s[nk][0] + s[nk][1]) + (s[nk][2] + s[nk][3]);
      }
      // ---- pack P to bf16 pairs
      unsigned pk[4][2];
      #pragma unroll
      for (int nk = 0; nk < 4; ++nk) {
        pk[nk][0] = cvtpk_bf16(s[nk][0], s[nk][1]);
        pk[nk][1] = cvtpk_bf16(s[nk][2], s[nk][3]);
      }
      // ---- O^T += mfma(V^T, P^T): B-frag pa[vks] = P[q=c][kv=32vks+8g+e]
      #pragma unroll
      for (int vks = 0; vks < 2; ++vks) {
        unsigned rA00 = __shfl(pk[2 * vks][0], srcA, 64);
        unsigned rA01 = __shfl(pk[2 * vks][1], srcA, 64);
        unsigned rA10 = __shfl(pk[2 * vks + 1][0], srcA, 64);
        unsigned rA11 = __shfl(pk[2 * vks + 1][1], srcA, 64);
        unsigned rB00 = __shfl(pk[2 * vks][0], srcB, 64);
        unsigned rB01 = __shfl(pk[2 * vks][1], srcB, 64);
        unsigned rB10 = __shfl(pk[2 * vks + 1][0], srcB, 64);
        unsigned rB11 = __shfl(pk[2 * vks + 1][1], srcB, 64);
        union { unsigned u[4]; bf16x8 v; } pa;
        pa.u[0] = hi ? rA10 : rA00;
        pa.u[1] = hi ? rA11 : rA01;
        pa.u[2] = hi ? rB10 : rB00;
        pa.u[3] = hi ? rB11 : rB01;
        bf16x8 vf[4];
        #pragma unroll
        for (int nd = 0; nd < 4; ++nd) {
          int row = nd * 16 + c;
          vf[nd] = *(const bf16x8*)(Vb + row * 128 + ((vks * 64 + g * 16) ^ ((row & 7) << 4)));
        }
        __builtin_amdgcn_s_setprio(1);
        #pragma unroll
        for (int nd = 0; nd < 4; ++nd)
          acc[nd] = __builtin_amdgcn_mfma_f32_16x16x32_bf16(vf[nd], pa.v, acc[nd], 0, 0, 0);
        __builtin_amdgcn_s_setprio(0);
      }
    }
    if (pre) {  // write prefetched V into next buffer (vmcnt wait lands here)
      char* Vbn = (char*)V_lds[cur ^ 1];
      #pragma unroll
      for (int jj = 0; jj < 4; ++jj) {
        int d = vcb * 4 + jj;
        int off = d * 128 + ((4 * vp) ^ ((d & 7) << 4));
        *(unsigned int*)(Vbn + off) = (unsigned int)v0n[jj] | ((unsigned int)v1n[jj] << 16);
      }
    }
    __syncthreads();  // one barrier per tile
  }

  // ---- epilogue: reduce l over the 4 g-lanes sharing q=c; write partials
  float lsum = lstate;
  lsum += __shfl_xor(lsum, 16);
  lsum += __shfl_xor(lsum, 32);
  const int qrow = w * 16 + c;                     // 0..127 within q-tile
  #pragma unroll
  for (int nd = 0; nd < 4; ++nd) {
    ushort4 o4;
    o4.x = f2b(acc[nd][0]); o4.y = f2b(acc[nd][1]);
    o4.z = f2b(acc[nd][2]); o4.w = f2b(acc[nd][3]);
    *(ushort4*)(partO + (size_t)bid * 8192 + qrow * 64 + nd * 16 + 4 * g) = o4;
  }
  if (g == 0) {
    partML[(size_t)bid * 256 + qrow * 2 + 0] = mstate;
    partML[(size_t)bid * 256 + qrow * 2 + 1] = lsum;
  }
}

// ---------------- combine: merge <=4 KV-chunk partials per 128-row q-tile ----
__global__ __launch_bounds__(256) void attn_combine(const unsigned short* __restrict__ partO,
                                                    const float* __restrict__ partML,
                                                    unsigned short* __restrict__ out) {
  const int bid = blockIdx.x;                      // 512 = 16 qt x 32 bh
  const int qt = bid >> 5, bh = bid & 31;
  const int b = bh >> 4, h = bh & 15;
  const int np = (2 * qt + 9) >> 3;                // ceil((2qt+2)/8)
  const int base = (qt < 4) ? qt
                 : (qt < 8) ? 4 + 2 * (qt - 4)
                 : (qt < 12) ? 12 + 3 * (qt - 8)
                 : 24 + 4 * (qt - 12);
  const int t = threadIdx.x;
  const int row = t >> 1, cg = (t & 1) * 32;       // 128 rows x 2 col-halves of 32
  const float SCL = 0.18033688f;
  float mstar = -1e30f;
  #pragma unroll
  for (int p = 0; p < 4; ++p)
    if (p < np)
      mstar = fmaxf(mstar, partML[(size_t)(((base + p) << 5) | bh) * 256 + row * 2]);
  float L = 0.f;
  float o[32];
  #pragma unroll
  for (int j = 0; j < 32; ++j) o[j] = 0.f;
  #pragma unroll
  for (int p = 0; p < 4; ++p) {
    if (p < np) {
      int slot = ((base + p) << 5) | bh;
      float mp = partML[(size_t)slot * 256 + row * 2 + 0];
      float lp = partML[(size_t)slot * 256 + row * 2 + 1];
      float wgt = exp2f((mp - mstar) * SCL);
      L = fmaf(wgt, lp, L);
      const unsigned short* src = partO + (size_t)slot * 8192 + row * 64 + cg;
      #pragma unroll
      for (int q = 0; q < 4; ++q) {
        u16x8 a = *(const u16x8*)(src + q * 8);
        #pragma unroll
        for (int j = 0; j < 8; ++j)
          o[q * 8 + j] = fmaf(b2f(a[j]), wgt, o[q * 8 + j]);
      }
    }
  }
  float rinv = 1.0f / L;
  size_t trow = (size_t)b * 2048 + qt * 128 + row;
  #pragma unroll
  for (int q = 0; q < 4; ++q) {
    u16x8 r;
    #pragma unroll
    for (int j = 0; j < 8; ++j) r[j] = f2b(o[q * 8 + j] * rinv);
    *(u16x8*)(out + trow * 1024 + h * 64 + cg + q * 8) = r;
  }
}

// ---------------- launch ----------------
extern "C" void kernel_launch(void* const* d_in, const int* in_sizes, int n_in,
                              void* d_out, int out_size, void* d_ws, size_t ws_size,
                              hipStream_t stream) {
  const float* x      = (const float*)d_in[0];
  const float* W_attn = (const float*)d_in[1];
  const float* b_attn = (const float*)d_in[2];
  const float* W_proj = (const float*)d_in[3];
  const float* b_proj = (const float*)d_in[4];
  float* out = (float*)d_out;

  char* ws = (char*)d_ws;
  unsigned short* Wproj_t  = (unsigned short*)(ws + 0);
  unsigned short* qkv      = (unsigned short*)(ws + 2097152);
  unsigned short* x_bf     = (unsigned short*)(ws + 27262976);
  unsigned short* Wattn_t  = (unsigned short*)(ws + 35651584);
  unsigned short* partO    = (unsigned short*)(ws + 27262976);   // overlaps x_bf/Wattn_t (dead)
  unsigned short* attn_out = (unsigned short*)(ws + 48234496);
  float*          partML   = (float*)(ws + 56623104);

  convert_f32_bf16<<<2048, 256, 0, stream>>>(x, x_bf, 4194304);
  transpose_f32_bf16<<<dim3(96, 32), dim3(32, 8), 0, stream>>>(W_attn, Wattn_t, 1024, 3072);
  transpose_f32_bf16<<<dim3(32, 32), dim3(32, 8), 0, stream>>>(W_proj, Wproj_t, 1024, 1024);

  gemm_bt<true><<<dim3(32, 24), 256, 0, stream>>>(x_bf, Wattn_t, b_attn, qkv, 4096, 3072, 1024);
  attn_kernel<<<1280, 512, 0, stream>>>(qkv, partO, partML);
  attn_combine<<<512, 256, 0, stream>>>(partO, partML, attn_out);
  gemm_bt<false><<<dim3(32, 8), 256, 0, stream>>>(attn_out, Wproj_t, b_proj, out, 4096, 1024, 1024);
}

// Round 11
// 151.438 us; speedup vs baseline: 1.5359x; 1.5359x over previous
//
#include <hip/hip_runtime.h>
#include <stdint.h>

typedef __attribute__((ext_vector_type(4))) float f32x4;
typedef __attribute__((ext_vector_type(8))) __bf16 bf16x8;
typedef __attribute__((ext_vector_type(8))) unsigned short u16x8;
typedef __attribute__((ext_vector_type(4))) unsigned short u16x4;

__device__ __forceinline__ unsigned short f2b(float f) {
  unsigned u = __float_as_uint(f);
  u += 0x7FFFu + ((u >> 16) & 1u);   // RNE
  return (unsigned short)(u >> 16);
}
__device__ __forceinline__ float b2f(unsigned short s) {
  unsigned u = (unsigned)s << 16;
  return __uint_as_float(u);
}
__device__ __forceinline__ unsigned cvtpk_bf16(float lo, float hi) {
  unsigned r;
  asm("v_cvt_pk_bf16_f32 %0, %1, %2" : "=v"(r) : "v"(lo), "v"(hi));
  return r;
}

__device__ __forceinline__ void gload_lds16(const void* g, void* l) {
  typedef __attribute__((address_space(1))) void GV1;
  typedef __attribute__((address_space(3))) void LV3;
  __builtin_amdgcn_global_load_lds((GV1*)(void*)g, (LV3*)l, 16, 0, 0);
}

// ---------------- conversion kernels ----------------
__global__ __launch_bounds__(256) void convert_f32_bf16(const float* __restrict__ in,
                                                        unsigned short* __restrict__ out, int n) {
  int i = (blockIdx.x * 256 + threadIdx.x) * 8;
  if (i >= n) return;
  float4 a = *(const float4*)(in + i);
  float4 b = *(const float4*)(in + i + 4);
  u16x8 r;
  r[0] = f2b(a.x); r[1] = f2b(a.y); r[2] = f2b(a.z); r[3] = f2b(a.w);
  r[4] = f2b(b.x); r[5] = f2b(b.y); r[6] = f2b(b.z); r[7] = f2b(b.w);
  *(u16x8*)(out + i) = r;
}

// W [K][N] f32 -> Wt [N][K] bf16
__global__ __launch_bounds__(256) void transpose_f32_bf16(const float* __restrict__ W,
                                                          unsigned short* __restrict__ Wt,
                                                          int K, int N) {
  __shared__ unsigned short tile[32][33];
  int n0 = blockIdx.x * 32, k0 = blockIdx.y * 32;
  int tx = threadIdx.x, ty = threadIdx.y;  // 32 x 8
  #pragma unroll
  for (int j = 0; j < 32; j += 8)
    tile[ty + j][tx] = f2b(W[(size_t)(k0 + ty + j) * N + n0 + tx]);
  __syncthreads();
  #pragma unroll
  for (int j = 0; j < 32; j += 8)
    Wt[(size_t)(n0 + ty + j) * K + k0 + tx] = tile[tx][ty + j];
}

// ---------------- GEMM: C[M][N] = A[M][K] * Bt[N][K]^T + bias ----------------
template <bool OUT_BF16>
__global__ __launch_bounds__(256) void gemm_bt(const unsigned short* __restrict__ A,
                                               const unsigned short* __restrict__ Bt,
                                               const float* __restrict__ bias,
                                               void* __restrict__ Cout,
                                               int M, int N, int K) {
  __shared__ unsigned short As[128 * 64];
  __shared__ unsigned short Bs[128 * 64];
  const int m0 = blockIdx.x * 128, n0 = blockIdx.y * 128;
  const int tid = threadIdx.x;
  const int w = tid >> 6, l = tid & 63;
  const int wm = w >> 1, wn = w & 1;
  const int c = l & 15, g = l >> 4;
  f32x4 acc[4][4] = {};
  for (int k0 = 0; k0 < K; k0 += 64) {
    #pragma unroll
    for (int i = 0; i < 4; ++i) {
      int rb = w * 32 + i * 8;
      gload_lds16(A + (size_t)(m0 + rb + (l >> 3)) * K + k0 + (l & 7) * 8, &As[rb * 64]);
      gload_lds16(Bt + (size_t)(n0 + rb + (l >> 3)) * K + k0 + (l & 7) * 8, &Bs[rb * 64]);
    }
    __syncthreads();
    #pragma unroll
    for (int ks = 0; ks < 2; ++ks) {
      bf16x8 af[4], bf[4];
      #pragma unroll
      for (int mi = 0; mi < 4; ++mi)
        af[mi] = *(const bf16x8*)&As[(wm * 64 + mi * 16 + c) * 64 + ks * 32 + g * 8];
      #pragma unroll
      for (int ni = 0; ni < 4; ++ni)
        bf[ni] = *(const bf16x8*)&Bs[(wn * 64 + ni * 16 + c) * 64 + ks * 32 + g * 8];
      #pragma unroll
      for (int mi = 0; mi < 4; ++mi)
        #pragma unroll
        for (int ni = 0; ni < 4; ++ni)
          acc[mi][ni] = __builtin_amdgcn_mfma_f32_16x16x32_bf16(af[mi], bf[ni], acc[mi][ni], 0, 0, 0);
    }
    __syncthreads();
  }
  #pragma unroll
  for (int mi = 0; mi < 4; ++mi) {
    #pragma unroll
    for (int ni = 0; ni < 4; ++ni) {
      int colg = n0 + wn * 64 + ni * 16 + c;
      float bv = bias[colg];
      #pragma unroll
      for (int r = 0; r < 4; ++r) {
        int rowg = m0 + wm * 64 + mi * 16 + 4 * g + r;
        float v = acc[mi][ni][r] + bv;
        if (OUT_BF16)
          ((unsigned short*)Cout)[(size_t)rowg * N + colg] = f2b(v);
        else
          ((float*)Cout)[(size_t)rowg * N + colg] = v;
      }
    }
  }
}

// ---------------- causal flash attention, SPLIT-KV + SWAPPED MFMA, QBLK=128 ----
// R10 post-mortem: __launch_bounds__(512,8) crushed VGPR to 32 -> scratch
// spills (FETCH 272MB, WRITE 199MB, attn 146us). THIS ROUND: identical kernel,
// __launch_bounds__(512) only (G1: declare only the occupancy you need).
// At ~68 VGPR: LDS allows 5 blk/CU, wave-cap 4 blk, VGPR ~7 waves/SIMD ->
// expect ~3 blocks/CU = 24 waves (2-3x R9's residency), spills gone.
__global__ __launch_bounds__(512) void attn_kernel(const unsigned short* __restrict__ qkv,
                                                   unsigned short* __restrict__ partO,
                                                   float* __restrict__ partML) {
  __shared__ unsigned short K_lds[2][64 * 64];     // [kv][d], XOR-swizzled rows
  __shared__ unsigned short V_lds[2][64 * 64];     // V^T [d][kv], XOR-swizzled rows
  const int bid = blockIdx.x;
  const int bh = bid & 31;
  const int cid = bid >> 5;                        // 0..39
  int qt, ct;
  if (cid < 4)       { qt = cid;            ct = 0; }
  else if (cid < 12) { int e = cid - 4;  qt = 4 + (e >> 1);  ct = e & 1; }
  else if (cid < 24) { int e = cid - 12; int q3 = e / 3; qt = 8 + q3; ct = e - 3 * q3; }
  else               { int e = cid - 24; qt = 12 + (e >> 2); ct = e & 3; }
  const int ntt = 2 * qt + 2;                      // total kv tiles for this q-tile
  const int t0 = ct * 8;
  const int ntl = min(ntt - t0, 8);                // tiles in this chunk (1..8)
  const int b = bh >> 4, h = bh & 15;
  const int tid = threadIdx.x, w = tid >> 6, l = tid & 63;
  const int c = l & 15, g = l >> 4;
  const int hi = g >> 1;
  const int srcA = c + ((g & 1) << 5);             // bpermute pattern A (j=0,1)
  const int srcB = srcA + 16;                      // pattern B (j=2,3)
  const size_t row0 = (size_t)b * 2048;
  const int vp = tid & 31, vcb = tid >> 5;         // V-stage: kv-pair, d-quad (0..15)
  const float SCL = 0.18033688f;                   // 0.125 * log2(e)

  const int q0w = qt * 128 + w * 16;
  const int qg = q0w + c;                          // this lane's q row (global)

  // Q fragments (B operand of swapped QK^T)
  bf16x8 qf[2];
  #pragma unroll
  for (int ks = 0; ks < 2; ++ks)
    qf[ks] = *(const bf16x8*)(qkv + (row0 + qg) * 3072 + h * 64 + ks * 32 + g * 8);

  f32x4 acc[4] = {};                               // O^T: acc[nd][r] = O[q=c][d=16nd+4g+r]
  float mstate = -1e30f, lstate = 0.f;

  // ---- prologue: stage kv-tile t0 into buffer 0
  {
    int rb = w * 8;                                // 8 waves x 8 rows = 64 kv
    int row = rb + (l >> 3);
    int ch = (l & 7) ^ (row & 7);                  // pre-swizzled source (m173)
    gload_lds16(qkv + (row0 + t0 * 64 + row) * 3072 + 1024 + h * 64 + ch * 8,
                &K_lds[0][rb * 64]);
    size_t tr = row0 + t0 * 64 + 2 * vp;
    u16x4 v0 = *(const u16x4*)(qkv + tr * 3072 + 2048 + h * 64 + vcb * 4);
    u16x4 v1 = *(const u16x4*)(qkv + (tr + 1) * 3072 + 2048 + h * 64 + vcb * 4);
    char* Vb = (char*)V_lds[0];
    #pragma unroll
    for (int jj = 0; jj < 4; ++jj) {
      int d = vcb * 4 + jj;
      int off = d * 128 + ((4 * vp) ^ ((d & 7) << 4));
      *(unsigned int*)(Vb + off) = (unsigned int)v0[jj] | ((unsigned int)v1[jj] << 16);
    }
  }
  __syncthreads();

  for (int lt = 0; lt < ntl; ++lt) {
    const int cur = lt & 1;
    const int kv0 = (t0 + lt) * 64;
    const bool pre = (lt + 1 < ntl);
    u16x4 v0n, v1n;
    if (pre) {  // issue next-tile loads BEFORE compute (2-phase pipeline)
      const int kvn = kv0 + 64;
      int rb = w * 8;
      int row = rb + (l >> 3);
      int ch = (l & 7) ^ (row & 7);
      gload_lds16(qkv + (row0 + kvn + row) * 3072 + 1024 + h * 64 + ch * 8,
                  &K_lds[cur ^ 1][rb * 64]);
      size_t tr = row0 + kvn + 2 * vp;
      v0n = *(const u16x4*)(qkv + tr * 3072 + 2048 + h * 64 + vcb * 4);
      v1n = *(const u16x4*)(qkv + (tr + 1) * 3072 + 2048 + h * 64 + vcb * 4);
    }
    if (kv0 <= q0w + 15) {  // wave-uniform: skip tiles fully above the diagonal
      const char* Kb = (const char*)K_lds[cur];
      const char* Vb = (const char*)V_lds[cur];
      // ---- S^T = mfma(K, Q): s[nk][r] = S[q=qg][kv = kv0 + 16nk + 4g + r]
      f32x4 s[4] = {};
      #pragma unroll
      for (int ks = 0; ks < 2; ++ks) {
        bf16x8 kf[4];
        #pragma unroll
        for (int nk = 0; nk < 4; ++nk) {
          int row = nk * 16 + c;
          kf[nk] = *(const bf16x8*)(Kb + row * 128 + ((ks * 64 + g * 16) ^ ((row & 7) << 4)));
        }
        __builtin_amdgcn_s_setprio(1);
        #pragma unroll
        for (int nk = 0; nk < 4; ++nk)
          s[nk] = __builtin_amdgcn_mfma_f32_16x16x32_bf16(kf[nk], qf[ks], s[nk], 0, 0, 0);
        __builtin_amdgcn_s_setprio(0);
      }
      // ---- causal mask on any tile straddling this wave's rows (wave-uniform)
      if (kv0 + 63 > q0w) {
        #pragma unroll
        for (int nk = 0; nk < 4; ++nk)
          #pragma unroll
          for (int r = 0; r < 4; ++r) {
            int kvg = kv0 + nk * 16 + 4 * g + r;
            if (kvg > qg) s[nk][r] = -1e30f;
          }
      }
      // ---- row max: in-lane tree + 2 shfls (lanes c,c+16,c+32,c+48 share q)
      float a0 = fmaxf(fmaxf(s[0][0], s[0][1]), fmaxf(s[0][2], s[0][3]));
      float a1 = fmaxf(fmaxf(s[1][0], s[1][1]), fmaxf(s[1][2], s[1][3]));
      float a2 = fmaxf(fmaxf(s[2][0], s[2][1]), fmaxf(s[2][2], s[2][3]));
      float a3 = fmaxf(fmaxf(s[3][0], s[3][1]), fmaxf(s[3][2], s[3][3]));
      float mx = fmaxf(fmaxf(a0, a1), fmaxf(a2, a3));
      mx = fmaxf(mx, __shfl_xor(mx, 16));
      mx = fmaxf(mx, __shfl_xor(mx, 32));
      // ---- alpha==1 fast path (wave-uniform); rescale lane-local
      if (!__all(mx <= mstate)) {
        float mnew = fmaxf(mstate, mx);
        float alpha = exp2f((mstate - mnew) * SCL);
        mstate = mnew;
        lstate *= alpha;
        #pragma unroll
        for (int nd = 0; nd < 4; ++nd) acc[nd] *= alpha;
      }
      // ---- P = exp2(s*SCL - m*SCL), per-lane l partial
      float ms = mstate * SCL;
      #pragma unroll
      for (int nk = 0; nk < 4; ++nk) {
        #pragma unroll
        for (int r = 0; r < 4; ++r) s[nk][r] = exp2f(fmaf(s[nk][r], SCL, -ms));
        lstate += (s[nk][0] + s[nk][1]) + (s[nk][2] + s[nk][3]);
      }
      // ---- pack P to bf16 pairs
      unsigned pk[4][2];
      #pragma unroll
      for (int nk = 0; nk < 4; ++nk) {
        pk[nk][0] = cvtpk_bf16(s[nk][0], s[nk][1]);
        pk[nk][1] = cvtpk_bf16(s[nk][2], s[nk][3]);
      }
      // ---- O^T += mfma(V^T, P^T): B-frag pa[vks] = P[q=c][kv=32vks+8g+e]
      #pragma unroll
      for (int vks = 0; vks < 2; ++vks) {
        unsigned rA00 = __shfl(pk[2 * vks][0], srcA, 64);
        unsigned rA01 = __shfl(pk[2 * vks][1], srcA, 64);
        unsigned rA10 = __shfl(pk[2 * vks + 1][0], srcA, 64);
        unsigned rA11 = __shfl(pk[2 * vks + 1][1], srcA, 64);
        unsigned rB00 = __shfl(pk[2 * vks][0], srcB, 64);
        unsigned rB01 = __shfl(pk[2 * vks][1], srcB, 64);
        unsigned rB10 = __shfl(pk[2 * vks + 1][0], srcB, 64);
        unsigned rB11 = __shfl(pk[2 * vks + 1][1], srcB, 64);
        union { unsigned u[4]; bf16x8 v; } pa;
        pa.u[0] = hi ? rA10 : rA00;
        pa.u[1] = hi ? rA11 : rA01;
        pa.u[2] = hi ? rB10 : rB00;
        pa.u[3] = hi ? rB11 : rB01;
        bf16x8 vf[4];
        #pragma unroll
        for (int nd = 0; nd < 4; ++nd) {
          int row = nd * 16 + c;
          vf[nd] = *(const bf16x8*)(Vb + row * 128 + ((vks * 64 + g * 16) ^ ((row & 7) << 4)));
        }
        __builtin_amdgcn_s_setprio(1);
        #pragma unroll
        for (int nd = 0; nd < 4; ++nd)
          acc[nd] = __builtin_amdgcn_mfma_f32_16x16x32_bf16(vf[nd], pa.v, acc[nd], 0, 0, 0);
        __builtin_amdgcn_s_setprio(0);
      }
    }
    if (pre) {  // write prefetched V into next buffer (vmcnt wait lands here)
      char* Vbn = (char*)V_lds[cur ^ 1];
      #pragma unroll
      for (int jj = 0; jj < 4; ++jj) {
        int d = vcb * 4 + jj;
        int off = d * 128 + ((4 * vp) ^ ((d & 7) << 4));
        *(unsigned int*)(Vbn + off) = (unsigned int)v0n[jj] | ((unsigned int)v1n[jj] << 16);
      }
    }
    __syncthreads();  // one barrier per tile
  }

  // ---- epilogue: reduce l over the 4 g-lanes sharing q=c; write partials
  float lsum = lstate;
  lsum += __shfl_xor(lsum, 16);
  lsum += __shfl_xor(lsum, 32);
  const int qrow = w * 16 + c;                     // 0..127 within q-tile
  #pragma unroll
  for (int nd = 0; nd < 4; ++nd) {
    ushort4 o4;
    o4.x = f2b(acc[nd][0]); o4.y = f2b(acc[nd][1]);
    o4.z = f2b(acc[nd][2]); o4.w = f2b(acc[nd][3]);
    *(ushort4*)(partO + (size_t)bid * 8192 + qrow * 64 + nd * 16 + 4 * g) = o4;
  }
  if (g == 0) {
    partML[(size_t)bid * 256 + qrow * 2 + 0] = mstate;
    partML[(size_t)bid * 256 + qrow * 2 + 1] = lsum;
  }
}

// ---------------- combine: merge <=4 KV-chunk partials per 128-row q-tile ----
__global__ __launch_bounds__(256) void attn_combine(const unsigned short* __restrict__ partO,
                                                    const float* __restrict__ partML,
                                                    unsigned short* __restrict__ out) {
  const int bid = blockIdx.x;                      // 512 = 16 qt x 32 bh
  const int qt = bid >> 5, bh = bid & 31;
  const int b = bh >> 4, h = bh & 15;
  const int np = (2 * qt + 9) >> 3;                // ceil((2qt+2)/8)
  const int base = (qt < 4) ? qt
                 : (qt < 8) ? 4 + 2 * (qt - 4)
                 : (qt < 12) ? 12 + 3 * (qt - 8)
                 : 24 + 4 * (qt - 12);
  const int t = threadIdx.x;
  const int row = t >> 1, cg = (t & 1) * 32;       // 128 rows x 2 col-halves of 32
  const float SCL = 0.18033688f;
  float mstar = -1e30f;
  #pragma unroll
  for (int p = 0; p < 4; ++p)
    if (p < np)
      mstar = fmaxf(mstar, partML[(size_t)(((base + p) << 5) | bh) * 256 + row * 2]);
  float L = 0.f;
  float o[32];
  #pragma unroll
  for (int j = 0; j < 32; ++j) o[j] = 0.f;
  #pragma unroll
  for (int p = 0; p < 4; ++p) {
    if (p < np) {
      int slot = ((base + p) << 5) | bh;
      float mp = partML[(size_t)slot * 256 + row * 2 + 0];
      float lp = partML[(size_t)slot * 256 + row * 2 + 1];
      float wgt = exp2f((mp - mstar) * SCL);
      L = fmaf(wgt, lp, L);
      const unsigned short* src = partO + (size_t)slot * 8192 + row * 64 + cg;
      #pragma unroll
      for (int q = 0; q < 4; ++q) {
        u16x8 a = *(const u16x8*)(src + q * 8);
        #pragma unroll
        for (int j = 0; j < 8; ++j)
          o[q * 8 + j] = fmaf(b2f(a[j]), wgt, o[q * 8 + j]);
      }
    }
  }
  float rinv = 1.0f / L;
  size_t trow = (size_t)b * 2048 + qt * 128 + row;
  #pragma unroll
  for (int q = 0; q < 4; ++q) {
    u16x8 r;
    #pragma unroll
    for (int j = 0; j < 8; ++j) r[j] = f2b(o[q * 8 + j] * rinv);
    *(u16x8*)(out + trow * 1024 + h * 64 + cg + q * 8) = r;
  }
}

// ---------------- launch ----------------
extern "C" void kernel_launch(void* const* d_in, const int* in_sizes, int n_in,
                              void* d_out, int out_size, void* d_ws, size_t ws_size,
                              hipStream_t stream) {
  const float* x      = (const float*)d_in[0];
  const float* W_attn = (const float*)d_in[1];
  const float* b_attn = (const float*)d_in[2];
  const float* W_proj = (const float*)d_in[3];
  const float* b_proj = (const float*)d_in[4];
  float* out = (float*)d_out;

  char* ws = (char*)d_ws;
  unsigned short* Wproj_t  = (unsigned short*)(ws + 0);
  unsigned short* qkv      = (unsigned short*)(ws + 2097152);
  unsigned short* x_bf     = (unsigned short*)(ws + 27262976);
  unsigned short* Wattn_t  = (unsigned short*)(ws + 35651584);
  unsigned short* partO    = (unsigned short*)(ws + 27262976);   // overlaps x_bf/Wattn_t (dead)
  unsigned short* attn_out = (unsigned short*)(ws + 48234496);
  float*          partML   = (float*)(ws + 56623104);

  convert_f32_bf16<<<2048, 256, 0, stream>>>(x, x_bf, 4194304);
  transpose_f32_bf16<<<dim3(96, 32), dim3(32, 8), 0, stream>>>(W_attn, Wattn_t, 1024, 3072);
  transpose_f32_bf16<<<dim3(32, 32), dim3(32, 8), 0, stream>>>(W_proj, Wproj_t, 1024, 1024);

  gemm_bt<true><<<dim3(32, 24), 256, 0, stream>>>(x_bf, Wattn_t, b_attn, qkv, 4096, 3072, 1024);
  attn_kernel<<<1280, 512, 0, stream>>>(qkv, partO, partML);
  attn_combine<<<512, 256, 0, stream>>>(partO, partML, attn_out);
  gemm_bt<false><<<dim3(32, 8), 256, 0, stream>>>(attn_out, Wproj_t, b_proj, out, 4096, 1024, 1024);
}

// Round 12
// 150.900 us; speedup vs baseline: 1.5414x; 1.0036x over previous
//
#include <hip/hip_runtime.h>
#include <stdint.h>

typedef __attribute__((ext_vector_type(4))) float f32x4;
typedef __attribute__((ext_vector_type(8))) __bf16 bf16x8;
typedef __attribute__((ext_vector_type(8))) unsigned short u16x8;
typedef __attribute__((ext_vector_type(4))) unsigned short u16x4;

__device__ __forceinline__ unsigned short f2b(float f) {
  unsigned u = __float_as_uint(f);
  u += 0x7FFFu + ((u >> 16) & 1u);   // RNE
  return (unsigned short)(u >> 16);
}
__device__ __forceinline__ float b2f(unsigned short s) {
  unsigned u = (unsigned)s << 16;
  return __uint_as_float(u);
}
__device__ __forceinline__ unsigned cvtpk_bf16(float lo, float hi) {
  unsigned r;
  asm("v_cvt_pk_bf16_f32 %0, %1, %2" : "=v"(r) : "v"(lo), "v"(hi));
  return r;
}

__device__ __forceinline__ void gload_lds16(const void* g, void* l) {
  typedef __attribute__((address_space(1))) void GV1;
  typedef __attribute__((address_space(3))) void LV3;
  __builtin_amdgcn_global_load_lds((GV1*)(void*)g, (LV3*)l, 16, 0, 0);
}

// ---------------- conversion kernels ----------------
__global__ __launch_bounds__(256) void convert_f32_bf16(const float* __restrict__ in,
                                                        unsigned short* __restrict__ out, int n) {
  int i = (blockIdx.x * 256 + threadIdx.x) * 8;
  if (i >= n) return;
  float4 a = *(const float4*)(in + i);
  float4 b = *(const float4*)(in + i + 4);
  u16x8 r;
  r[0] = f2b(a.x); r[1] = f2b(a.y); r[2] = f2b(a.z); r[3] = f2b(a.w);
  r[4] = f2b(b.x); r[5] = f2b(b.y); r[6] = f2b(b.z); r[7] = f2b(b.w);
  *(u16x8*)(out + i) = r;
}

// W [K][N] f32 -> Wt [N][K] bf16
__global__ __launch_bounds__(256) void transpose_f32_bf16(const float* __restrict__ W,
                                                          unsigned short* __restrict__ Wt,
                                                          int K, int N) {
  __shared__ unsigned short tile[32][33];
  int n0 = blockIdx.x * 32, k0 = blockIdx.y * 32;
  int tx = threadIdx.x, ty = threadIdx.y;  // 32 x 8
  #pragma unroll
  for (int j = 0; j < 32; j += 8)
    tile[ty + j][tx] = f2b(W[(size_t)(k0 + ty + j) * N + n0 + tx]);
  __syncthreads();
  #pragma unroll
  for (int j = 0; j < 32; j += 8)
    Wt[(size_t)(n0 + ty + j) * K + k0 + tx] = tile[tx][ty + j];
}

// ---------------- GEMM: C[M][N] = A[M][K] * Bt[N][K]^T + bias ----------------
template <bool OUT_BF16>
__global__ __launch_bounds__(256) void gemm_bt(const unsigned short* __restrict__ A,
                                               const unsigned short* __restrict__ Bt,
                                               const float* __restrict__ bias,
                                               void* __restrict__ Cout,
                                               int M, int N, int K) {
  __shared__ unsigned short As[128 * 64];
  __shared__ unsigned short Bs[128 * 64];
  const int m0 = blockIdx.x * 128, n0 = blockIdx.y * 128;
  const int tid = threadIdx.x;
  const int w = tid >> 6, l = tid & 63;
  const int wm = w >> 1, wn = w & 1;
  const int c = l & 15, g = l >> 4;
  f32x4 acc[4][4] = {};
  for (int k0 = 0; k0 < K; k0 += 64) {
    #pragma unroll
    for (int i = 0; i < 4; ++i) {
      int rb = w * 32 + i * 8;
      gload_lds16(A + (size_t)(m0 + rb + (l >> 3)) * K + k0 + (l & 7) * 8, &As[rb * 64]);
      gload_lds16(Bt + (size_t)(n0 + rb + (l >> 3)) * K + k0 + (l & 7) * 8, &Bs[rb * 64]);
    }
    __syncthreads();
    #pragma unroll
    for (int ks = 0; ks < 2; ++ks) {
      bf16x8 af[4], bf[4];
      #pragma unroll
      for (int mi = 0; mi < 4; ++mi)
        af[mi] = *(const bf16x8*)&As[(wm * 64 + mi * 16 + c) * 64 + ks * 32 + g * 8];
      #pragma unroll
      for (int ni = 0; ni < 4; ++ni)
        bf[ni] = *(const bf16x8*)&Bs[(wn * 64 + ni * 16 + c) * 64 + ks * 32 + g * 8];
      #pragma unroll
      for (int mi = 0; mi < 4; ++mi)
        #pragma unroll
        for (int ni = 0; ni < 4; ++ni)
          acc[mi][ni] = __builtin_amdgcn_mfma_f32_16x16x32_bf16(af[mi], bf[ni], acc[mi][ni], 0, 0, 0);
    }
    __syncthreads();
  }
  #pragma unroll
  for (int mi = 0; mi < 4; ++mi) {
    #pragma unroll
    for (int ni = 0; ni < 4; ++ni) {
      int colg = n0 + wn * 64 + ni * 16 + c;
      float bv = bias[colg];
      #pragma unroll
      for (int r = 0; r < 4; ++r) {
        int rowg = m0 + wm * 64 + mi * 16 + 4 * g + r;
        float v = acc[mi][ni][r] + bv;
        if (OUT_BF16)
          ((unsigned short*)Cout)[(size_t)rowg * N + colg] = f2b(v);
        else
          ((float*)Cout)[(size_t)rowg * N + colg] = v;
      }
    }
  }
}

// ---------------- causal flash attention, SPLIT-KV + SWAPPED MFMA, QBLK=128 ----
// R11: attn 65us, occ 32% though static limits allow 4 blk/CU. H4: dispatch-
// order tail — old map put all ntl=8 chunks LAST (cid 24..39). THIS ROUND:
// heavy-first via cid = 39 - bid/32 (tail becomes 2-tile blocks) + global
// pointers hoisted out of the tile loop (advance by 64*3072/tile, kills
// per-tile 64-bit remultiplies). Inner loop otherwise byte-identical to R11.
__global__ __launch_bounds__(512) void attn_kernel(const unsigned short* __restrict__ qkv,
                                                   unsigned short* __restrict__ partO,
                                                   float* __restrict__ partML) {
  __shared__ unsigned short K_lds[2][64 * 64];     // [kv][d], XOR-swizzled rows
  __shared__ unsigned short V_lds[2][64 * 64];     // V^T [d][kv], XOR-swizzled rows
  const int bid = blockIdx.x;
  const int bh = bid & 31;
  const int cid = 39 - (bid >> 5);                 // HEAVY-FIRST (was: bid>>5)
  int qt, ct;
  if (cid < 4)       { qt = cid;            ct = 0; }
  else if (cid < 12) { int e = cid - 4;  qt = 4 + (e >> 1);  ct = e & 1; }
  else if (cid < 24) { int e = cid - 12; int q3 = e / 3; qt = 8 + q3; ct = e - 3 * q3; }
  else               { int e = cid - 24; qt = 12 + (e >> 2); ct = e & 3; }
  const int ntt = 2 * qt + 2;                      // total kv tiles for this q-tile
  const int t0 = ct * 8;
  const int ntl = min(ntt - t0, 8);                // tiles in this chunk (1..8)
  const int b = bh >> 4, h = bh & 15;
  const int tid = threadIdx.x, w = tid >> 6, l = tid & 63;
  const int c = l & 15, g = l >> 4;
  const int hi = g >> 1;
  const int srcA = c + ((g & 1) << 5);             // bpermute pattern A (j=0,1)
  const int srcB = srcA + 16;                      // pattern B (j=2,3)
  const size_t row0 = (size_t)b * 2048;
  const int vp = tid & 31, vcb = tid >> 5;         // V-stage: kv-pair, d-quad (0..15)
  const float SCL = 0.18033688f;                   // 0.125 * log2(e)
  const int TSTRIDE = 64 * 3072;                   // elems per kv-tile step

  const int q0w = qt * 128 + w * 16;
  const int qg = q0w + c;                          // this lane's q row (global)

  // Q fragments (B operand of swapped QK^T)
  bf16x8 qf[2];
  #pragma unroll
  for (int ks = 0; ks < 2; ++ks)
    qf[ks] = *(const bf16x8*)(qkv + (row0 + qg) * 3072 + h * 64 + ks * 32 + g * 8);

  f32x4 acc[4] = {};                               // O^T: acc[nd][r] = O[q=c][d=16nd+4g+r]
  float mstate = -1e30f, lstate = 0.f;

  // ---- hoisted per-lane global pointers (advance by TSTRIDE per tile)
  const int krow = w * 8 + (l >> 3);               // this lane's K row in tile
  const int kch = (l & 7) ^ (krow & 7);            // pre-swizzled source chunk (m173)
  const unsigned short* kptr = qkv + (row0 + t0 * 64 + krow) * 3072 + 1024 + h * 64 + kch * 8;
  const unsigned short* vptr = qkv + (row0 + t0 * 64 + 2 * vp) * 3072 + 2048 + h * 64 + vcb * 4;
  const int kdst = (w * 8) * 64;                   // wave-uniform LDS base (elems)
  int voff[4];
  #pragma unroll
  for (int jj = 0; jj < 4; ++jj) {
    int d = vcb * 4 + jj;
    voff[jj] = d * 128 + ((4 * vp) ^ ((d & 7) << 4));
  }

  // ---- prologue: stage kv-tile t0 into buffer 0
  {
    gload_lds16(kptr, &K_lds[0][kdst]);
    u16x4 v0 = *(const u16x4*)vptr;
    u16x4 v1 = *(const u16x4*)(vptr + 3072);
    char* Vb = (char*)V_lds[0];
    #pragma unroll
    for (int jj = 0; jj < 4; ++jj)
      *(unsigned int*)(Vb + voff[jj]) = (unsigned int)v0[jj] | ((unsigned int)v1[jj] << 16);
  }
  __syncthreads();

  for (int lt = 0; lt < ntl; ++lt) {
    const int cur = lt & 1;
    const int kv0 = (t0 + lt) * 64;
    const bool pre = (lt + 1 < ntl);
    u16x4 v0n, v1n;
    if (pre) {  // issue next-tile loads BEFORE compute (2-phase pipeline)
      gload_lds16(kptr + TSTRIDE, &K_lds[cur ^ 1][kdst]);
      v0n = *(const u16x4*)(vptr + TSTRIDE);
      v1n = *(const u16x4*)(vptr + TSTRIDE + 3072);
    }
    kptr += TSTRIDE;
    vptr += TSTRIDE;
    if (kv0 <= q0w + 15) {  // wave-uniform: skip tiles fully above the diagonal
      const char* Kb = (const char*)K_lds[cur];
      const char* Vb = (const char*)V_lds[cur];
      // ---- S^T = mfma(K, Q): s[nk][r] = S[q=qg][kv = kv0 + 16nk + 4g + r]
      f32x4 s[4] = {};
      #pragma unroll
      for (int ks = 0; ks < 2; ++ks) {
        bf16x8 kf[4];
        #pragma unroll
        for (int nk = 0; nk < 4; ++nk) {
          int row = nk * 16 + c;
          kf[nk] = *(const bf16x8*)(Kb + row * 128 + ((ks * 64 + g * 16) ^ ((row & 7) << 4)));
        }
        __builtin_amdgcn_s_setprio(1);
        #pragma unroll
        for (int nk = 0; nk < 4; ++nk)
          s[nk] = __builtin_amdgcn_mfma_f32_16x16x32_bf16(kf[nk], qf[ks], s[nk], 0, 0, 0);
        __builtin_amdgcn_s_setprio(0);
      }
      // ---- causal mask on any tile straddling this wave's rows (wave-uniform)
      if (kv0 + 63 > q0w) {
        #pragma unroll
        for (int nk = 0; nk < 4; ++nk)
          #pragma unroll
          for (int r = 0; r < 4; ++r) {
            int kvg = kv0 + nk * 16 + 4 * g + r;
            if (kvg > qg) s[nk][r] = -1e30f;
          }
      }
      // ---- row max: in-lane tree + 2 shfls (lanes c,c+16,c+32,c+48 share q)
      float a0 = fmaxf(fmaxf(s[0][0], s[0][1]), fmaxf(s[0][2], s[0][3]));
      float a1 = fmaxf(fmaxf(s[1][0], s[1][1]), fmaxf(s[1][2], s[1][3]));
      float a2 = fmaxf(fmaxf(s[2][0], s[2][1]), fmaxf(s[2][2], s[2][3]));
      float a3 = fmaxf(fmaxf(s[3][0], s[3][1]), fmaxf(s[3][2], s[3][3]));
      float mx = fmaxf(fmaxf(a0, a1), fmaxf(a2, a3));
      mx = fmaxf(mx, __shfl_xor(mx, 16));
      mx = fmaxf(mx, __shfl_xor(mx, 32));
      // ---- alpha==1 fast path (wave-uniform); rescale lane-local
      if (!__all(mx <= mstate)) {
        float mnew = fmaxf(mstate, mx);
        float alpha = exp2f((mstate - mnew) * SCL);
        mstate = mnew;
        lstate *= alpha;
        #pragma unroll
        for (int nd = 0; nd < 4; ++nd) acc[nd] *= alpha;
      }
      // ---- P = exp2(s*SCL - m*SCL), per-lane l partial
      float ms = mstate * SCL;
      #pragma unroll
      for (int nk = 0; nk < 4; ++nk) {
        #pragma unroll
        for (int r = 0; r < 4; ++r) s[nk][r] = exp2f(fmaf(s[nk][r], SCL, -ms));
        lstate += (s[nk][0] + s[nk][1]) + (s[nk][2] + s[nk][3]);
      }
      // ---- pack P to bf16 pairs
      unsigned pk[4][2];
      #pragma unroll
      for (int nk = 0; nk < 4; ++nk) {
        pk[nk][0] = cvtpk_bf16(s[nk][0], s[nk][1]);
        pk[nk][1] = cvtpk_bf16(s[nk][2], s[nk][3]);
      }
      // ---- O^T += mfma(V^T, P^T): B-frag pa[vks] = P[q=c][kv=32vks+8g+e]
      #pragma unroll
      for (int vks = 0; vks < 2; ++vks) {
        unsigned rA00 = __shfl(pk[2 * vks][0], srcA, 64);
        unsigned rA01 = __shfl(pk[2 * vks][1], srcA, 64);
        unsigned rA10 = __shfl(pk[2 * vks + 1][0], srcA, 64);
        unsigned rA11 = __shfl(pk[2 * vks + 1][1], srcA, 64);
        unsigned rB00 = __shfl(pk[2 * vks][0], srcB, 64);
        unsigned rB01 = __shfl(pk[2 * vks][1], srcB, 64);
        unsigned rB10 = __shfl(pk[2 * vks + 1][0], srcB, 64);
        unsigned rB11 = __shfl(pk[2 * vks + 1][1], srcB, 64);
        union { unsigned u[4]; bf16x8 v; } pa;
        pa.u[0] = hi ? rA10 : rA00;
        pa.u[1] = hi ? rA11 : rA01;
        pa.u[2] = hi ? rB10 : rB00;
        pa.u[3] = hi ? rB11 : rB01;
        bf16x8 vf[4];
        #pragma unroll
        for (int nd = 0; nd < 4; ++nd) {
          int row = nd * 16 + c;
          vf[nd] = *(const bf16x8*)(Vb + row * 128 + ((vks * 64 + g * 16) ^ ((row & 7) << 4)));
        }
        __builtin_amdgcn_s_setprio(1);
        #pragma unroll
        for (int nd = 0; nd < 4; ++nd)
          acc[nd] = __builtin_amdgcn_mfma_f32_16x16x32_bf16(vf[nd], pa.v, acc[nd], 0, 0, 0);
        __builtin_amdgcn_s_setprio(0);
      }
    }
    if (pre) {  // write prefetched V into next buffer (vmcnt wait lands here)
      char* Vbn = (char*)V_lds[cur ^ 1];
      #pragma unroll
      for (int jj = 0; jj < 4; ++jj)
        *(unsigned int*)(Vbn + voff[jj]) = (unsigned int)v0n[jj] | ((unsigned int)v1n[jj] << 16);
    }
    __syncthreads();  // one barrier per tile
  }

  // ---- epilogue: reduce l over the 4 g-lanes sharing q=c; write partials
  float lsum = lstate;
  lsum += __shfl_xor(lsum, 16);
  lsum += __shfl_xor(lsum, 32);
  const int qrow = w * 16 + c;                     // 0..127 within q-tile
  #pragma unroll
  for (int nd = 0; nd < 4; ++nd) {
    ushort4 o4;
    o4.x = f2b(acc[nd][0]); o4.y = f2b(acc[nd][1]);
    o4.z = f2b(acc[nd][2]); o4.w = f2b(acc[nd][3]);
    *(ushort4*)(partO + (size_t)bid * 8192 + qrow * 64 + nd * 16 + 4 * g) = o4;
  }
  if (g == 0) {
    partML[(size_t)bid * 256 + qrow * 2 + 0] = mstate;
    partML[(size_t)bid * 256 + qrow * 2 + 1] = lsum;
  }
}

// ---------------- combine: merge <=4 KV-chunk partials per 128-row q-tile ----
__global__ __launch_bounds__(256) void attn_combine(const unsigned short* __restrict__ partO,
                                                    const float* __restrict__ partML,
                                                    unsigned short* __restrict__ out) {
  const int bid = blockIdx.x;                      // 512 = 16 qt x 32 bh
  const int qt = bid >> 5, bh = bid & 31;
  const int b = bh >> 4, h = bh & 15;
  const int np = (2 * qt + 9) >> 3;                // ceil((2qt+2)/8)
  const int base = (qt < 4) ? qt
                 : (qt < 8) ? 4 + 2 * (qt - 4)
                 : (qt < 12) ? 12 + 3 * (qt - 8)
                 : 24 + 4 * (qt - 12);
  const int t = threadIdx.x;
  const int row = t >> 1, cg = (t & 1) * 32;       // 128 rows x 2 col-halves of 32
  const float SCL = 0.18033688f;
  // attn dispatches chunk cid_work at raw bid-chunk (39 - cid_work)
  float mstar = -1e30f;
  #pragma unroll
  for (int p = 0; p < 4; ++p)
    if (p < np)
      mstar = fmaxf(mstar, partML[(size_t)(((39 - (base + p)) << 5) | bh) * 256 + row * 2]);
  float L = 0.f;
  float o[32];
  #pragma unroll
  for (int j = 0; j < 32; ++j) o[j] = 0.f;
  #pragma unroll
  for (int p = 0; p < 4; ++p) {
    if (p < np) {
      int slot = ((39 - (base + p)) << 5) | bh;
      float mp = partML[(size_t)slot * 256 + row * 2 + 0];
      float lp = partML[(size_t)slot * 256 + row * 2 + 1];
      float wgt = exp2f((mp - mstar) * SCL);
      L = fmaf(wgt, lp, L);
      const unsigned short* src = partO + (size_t)slot * 8192 + row * 64 + cg;
      #pragma unroll
      for (int q = 0; q < 4; ++q) {
        u16x8 a = *(const u16x8*)(src + q * 8);
        #pragma unroll
        for (int j = 0; j < 8; ++j)
          o[q * 8 + j] = fmaf(b2f(a[j]), wgt, o[q * 8 + j]);
      }
    }
  }
  float rinv = 1.0f / L;
  size_t trow = (size_t)b * 2048 + qt * 128 + row;
  #pragma unroll
  for (int q = 0; q < 4; ++q) {
    u16x8 r;
    #pragma unroll
    for (int j = 0; j < 8; ++j) r[j] = f2b(o[q * 8 + j] * rinv);
    *(u16x8*)(out + trow * 1024 + h * 64 + cg + q * 8) = r;
  }
}

// ---------------- launch ----------------
extern "C" void kernel_launch(void* const* d_in, const int* in_sizes, int n_in,
                              void* d_out, int out_size, void* d_ws, size_t ws_size,
                              hipStream_t stream) {
  const float* x      = (const float*)d_in[0];
  const float* W_attn = (const float*)d_in[1];
  const float* b_attn = (const float*)d_in[2];
  const float* W_proj = (const float*)d_in[3];
  const float* b_proj = (const float*)d_in[4];
  float* out = (float*)d_out;

  char* ws = (char*)d_ws;
  unsigned short* Wproj_t  = (unsigned short*)(ws + 0);
  unsigned short* qkv      = (unsigned short*)(ws + 2097152);
  unsigned short* x_bf     = (unsigned short*)(ws + 27262976);
  unsigned short* Wattn_t  = (unsigned short*)(ws + 35651584);
  unsigned short* partO    = (unsigned short*)(ws + 27262976);   // overlaps x_bf/Wattn_t (dead)
  unsigned short* attn_out = (unsigned short*)(ws + 48234496);
  float*          partML   = (float*)(ws + 56623104);

  convert_f32_bf16<<<2048, 256, 0, stream>>>(x, x_bf, 4194304);
  transpose_f32_bf16<<<dim3(96, 32), dim3(32, 8), 0, stream>>>(W_attn, Wattn_t, 1024, 3072);
  transpose_f32_bf16<<<dim3(32, 32), dim3(32, 8), 0, stream>>>(W_proj, Wproj_t, 1024, 1024);

  gemm_bt<true><<<dim3(32, 24), 256, 0, stream>>>(x_bf, Wattn_t, b_attn, qkv, 4096, 3072, 1024);
  attn_kernel<<<1280, 512, 0, stream>>>(qkv, partO, partML);
  attn_combine<<<512, 256, 0, stream>>>(partO, partML, attn_out);
  gemm_bt<false><<<dim3(32, 8), 256, 0, stream>>>(attn_out, Wproj_t, b_proj, out, 4096, 1024, 1024);
}

// Round 13
// 148.385 us; speedup vs baseline: 1.5675x; 1.0170x over previous
//
#include <hip/hip_runtime.h>
#include <stdint.h>

typedef __attribute__((ext_vector_type(4))) float f32x4;
typedef __attribute__((ext_vector_type(8))) __bf16 bf16x8;
typedef __attribute__((ext_vector_type(8))) unsigned short u16x8;

__device__ __forceinline__ unsigned short f2b(float f) {
  unsigned u = __float_as_uint(f);
  u += 0x7FFFu + ((u >> 16) & 1u);   // RNE
  return (unsigned short)(u >> 16);
}
__device__ __forceinline__ float b2f(unsigned short s) {
  unsigned u = (unsigned)s << 16;
  return __uint_as_float(u);
}
__device__ __forceinline__ unsigned cvtpk_bf16(float lo, float hi) {
  unsigned r;
  asm("v_cvt_pk_bf16_f32 %0, %1, %2" : "=v"(r) : "v"(lo), "v"(hi));
  return r;
}

__device__ __forceinline__ void gload_lds16(const void* g, void* l) {
  typedef __attribute__((address_space(1))) void GV1;
  typedef __attribute__((address_space(3))) void LV3;
  __builtin_amdgcn_global_load_lds((GV1*)(void*)g, (LV3*)l, 16, 0, 0);
}

// ---------------- conversion kernels ----------------
__global__ __launch_bounds__(256) void convert_f32_bf16(const float* __restrict__ in,
                                                        unsigned short* __restrict__ out, int n) {
  int i = (blockIdx.x * 256 + threadIdx.x) * 8;
  if (i >= n) return;
  float4 a = *(const float4*)(in + i);
  float4 b = *(const float4*)(in + i + 4);
  u16x8 r;
  r[0] = f2b(a.x); r[1] = f2b(a.y); r[2] = f2b(a.z); r[3] = f2b(a.w);
  r[4] = f2b(b.x); r[5] = f2b(b.y); r[6] = f2b(b.z); r[7] = f2b(b.w);
  *(u16x8*)(out + i) = r;
}

// W [K][N] f32 -> Wt [N][K] bf16
__global__ __launch_bounds__(256) void transpose_f32_bf16(const float* __restrict__ W,
                                                          unsigned short* __restrict__ Wt,
                                                          int K, int N) {
  __shared__ unsigned short tile[32][33];
  int n0 = blockIdx.x * 32, k0 = blockIdx.y * 32;
  int tx = threadIdx.x, ty = threadIdx.y;  // 32 x 8
  #pragma unroll
  for (int j = 0; j < 32; j += 8)
    tile[ty + j][tx] = f2b(W[(size_t)(k0 + ty + j) * N + n0 + tx]);
  __syncthreads();
  #pragma unroll
  for (int j = 0; j < 32; j += 8)
    Wt[(size_t)(n0 + ty + j) * K + k0 + tx] = tile[tx][ty + j];
}

// ---------------- GEMM: C[M][N] = A[M][K] * Bt[N][K]^T + bias ----------------
// VSPLIT (GEMM1 only): cols <2048 (Q,K) -> bf16 qk buffer stride 2048;
// cols >=2048 (V) -> TRANSPOSED bf16 write to vT[1024][4096] via LDS
// (one-time transpose here so attention can stage V^T with a coalesced
// global_load_lds, identical to K staging).
template <bool OUT_BF16, bool VSPLIT>
__global__ __launch_bounds__(256) void gemm_bt(const unsigned short* __restrict__ A,
                                               const unsigned short* __restrict__ Bt,
                                               const float* __restrict__ bias,
                                               void* __restrict__ Cout,
                                               unsigned short* __restrict__ vT,
                                               int M, int N, int K) {
  __shared__ unsigned short SMEM[128 * 136];       // As(8192) + Bs(8192); reused as T[128][136]
  unsigned short* As = SMEM;
  unsigned short* Bs = SMEM + 8192;
  const int m0 = blockIdx.x * 128, n0 = blockIdx.y * 128;
  const int tid = threadIdx.x;
  const int w = tid >> 6, l = tid & 63;
  const int wm = w >> 1, wn = w & 1;
  const int c = l & 15, g = l >> 4;
  f32x4 acc[4][4] = {};
  for (int k0 = 0; k0 < K; k0 += 64) {
    #pragma unroll
    for (int i = 0; i < 4; ++i) {
      int rb = w * 32 + i * 8;
      gload_lds16(A + (size_t)(m0 + rb + (l >> 3)) * K + k0 + (l & 7) * 8, &As[rb * 64]);
      gload_lds16(Bt + (size_t)(n0 + rb + (l >> 3)) * K + k0 + (l & 7) * 8, &Bs[rb * 64]);
    }
    __syncthreads();
    #pragma unroll
    for (int ks = 0; ks < 2; ++ks) {
      bf16x8 af[4], bf[4];
      #pragma unroll
      for (int mi = 0; mi < 4; ++mi)
        af[mi] = *(const bf16x8*)&As[(wm * 64 + mi * 16 + c) * 64 + ks * 32 + g * 8];
      #pragma unroll
      for (int ni = 0; ni < 4; ++ni)
        bf[ni] = *(const bf16x8*)&Bs[(wn * 64 + ni * 16 + c) * 64 + ks * 32 + g * 8];
      #pragma unroll
      for (int mi = 0; mi < 4; ++mi)
        #pragma unroll
        for (int ni = 0; ni < 4; ++ni)
          acc[mi][ni] = __builtin_amdgcn_mfma_f32_16x16x32_bf16(af[mi], bf[ni], acc[mi][ni], 0, 0, 0);
    }
    __syncthreads();
  }
  if (VSPLIT && n0 >= 2048) {
    // ---- V block: transpose via LDS, coalesced write to vT[d][t]
    #pragma unroll
    for (int mi = 0; mi < 4; ++mi)
      #pragma unroll
      for (int ni = 0; ni < 4; ++ni) {
        int cl = wn * 64 + ni * 16 + c;
        float bv = bias[n0 + cl];
        #pragma unroll
        for (int r = 0; r < 4; ++r) {
          int rl = wm * 64 + mi * 16 + 4 * g + r;
          SMEM[cl * 136 + rl] = f2b(acc[mi][ni][r] + bv);
        }
      }
    __syncthreads();
    const int d0 = n0 - 2048;
    #pragma unroll
    for (int p = 0; p < 8; ++p) {
      int rowl = p * 16 + (tid >> 4);
      *(u16x8*)(vT + (size_t)(d0 + rowl) * 4096 + m0 + (tid & 15) * 8) =
          *(const u16x8*)&SMEM[rowl * 136 + (tid & 15) * 8];
    }
    return;
  }
  const int NS = VSPLIT ? 2048 : N;                // qk buffer stride for VSPLIT
  #pragma unroll
  for (int mi = 0; mi < 4; ++mi) {
    #pragma unroll
    for (int ni = 0; ni < 4; ++ni) {
      int colg = n0 + wn * 64 + ni * 16 + c;
      float bv = bias[colg];
      #pragma unroll
      for (int r = 0; r < 4; ++r) {
        int rowg = m0 + wm * 64 + mi * 16 + 4 * g + r;
        float v = acc[mi][ni][r] + bv;
        if (OUT_BF16)
          ((unsigned short*)Cout)[(size_t)rowg * NS + colg] = f2b(v);
        else
          ((float*)Cout)[(size_t)rowg * NS + colg] = v;
      }
    }
  }
}

// ---------------- causal flash attention, SPLIT-KV + SWAPPED MFMA, QBLK=128 ----
// R12: V staging was the last uncoalesced path (64 lanes x 8B at 12KB stride +
// pack VALU + swizzled ds_writes per tile). GEMM1 now emits vT[1024][4096]
// (V^T), so V stages with ONE coalesced global_load_lds mirroring K: same
// source pre-swizzle (m173), same XOR'd read path, fully async prefetch.
// qk buffer is [4096][2048] (Q,K only, stride 2048).
__global__ __launch_bounds__(512) void attn_kernel(const unsigned short* __restrict__ qk,
                                                   const unsigned short* __restrict__ vT,
                                                   unsigned short* __restrict__ partO,
                                                   float* __restrict__ partML) {
  __shared__ unsigned short K_lds[2][64 * 64];     // [kv][d], XOR-swizzled rows
  __shared__ unsigned short V_lds[2][64 * 64];     // V^T [d][kv], XOR-swizzled rows
  const int bid = blockIdx.x;
  const int bh = bid & 31;
  const int cid = 39 - (bid >> 5);                 // heavy-first
  int qt, ct;
  if (cid < 4)       { qt = cid;            ct = 0; }
  else if (cid < 12) { int e = cid - 4;  qt = 4 + (e >> 1);  ct = e & 1; }
  else if (cid < 24) { int e = cid - 12; int q3 = e / 3; qt = 8 + q3; ct = e - 3 * q3; }
  else               { int e = cid - 24; qt = 12 + (e >> 2); ct = e & 3; }
  const int ntt = 2 * qt + 2;                      // total kv tiles for this q-tile
  const int t0 = ct * 8;
  const int ntl = min(ntt - t0, 8);                // tiles in this chunk (1..8)
  const int b = bh >> 4, h = bh & 15;
  const int tid = threadIdx.x, w = tid >> 6, l = tid & 63;
  const int c = l & 15, g = l >> 4;
  const int hi = g >> 1;
  const int srcA = c + ((g & 1) << 5);             // bpermute pattern A (j=0,1)
  const int srcB = srcA + 16;                      // pattern B (j=2,3)
  const size_t row0 = (size_t)b * 2048;
  const float SCL = 0.18033688f;                   // 0.125 * log2(e)
  const int KSTRIDE = 64 * 2048;                   // qk elems per kv-tile step
  const int VSTRIDE = 64;                          // vT elems per kv-tile step

  const int q0w = qt * 128 + w * 16;
  const int qg = q0w + c;                          // this lane's q row (global)

  // Q fragments (B operand of swapped QK^T)
  bf16x8 qf[2];
  #pragma unroll
  for (int ks = 0; ks < 2; ++ks)
    qf[ks] = *(const bf16x8*)(qk + (row0 + qg) * 2048 + h * 64 + ks * 32 + g * 8);

  f32x4 acc[4] = {};                               // O^T: acc[nd][r] = O[q=c][d=16nd+4g+r]
  float mstate = -1e30f, lstate = 0.f;

  // ---- hoisted per-lane global pointers (advance per tile)
  const int krow = w * 8 + (l >> 3);               // lane's row in tile (K: kv; V: d)
  const int kch = (l & 7) ^ (krow & 7);            // pre-swizzled source chunk (m173)
  const unsigned short* kptr = qk + (row0 + t0 * 64 + krow) * 2048 + 1024 + h * 64 + kch * 8;
  const unsigned short* vptr = vT + (size_t)(h * 64 + krow) * 4096 + (b * 2048 + t0 * 64) + kch * 8;
  const int kdst = (w * 8) * 64;                   // wave-uniform LDS base (elems)

  // ---- prologue: stage kv-tile t0 into buffer 0 (both fully async)
  gload_lds16(kptr, &K_lds[0][kdst]);
  gload_lds16(vptr, &V_lds[0][kdst]);
  __syncthreads();

  for (int lt = 0; lt < ntl; ++lt) {
    const int cur = lt & 1;
    const int kv0 = (t0 + lt) * 64;
    const bool pre = (lt + 1 < ntl);
    if (pre) {  // issue next-tile async loads BEFORE compute (2-phase pipeline)
      gload_lds16(kptr + KSTRIDE, &K_lds[cur ^ 1][kdst]);
      gload_lds16(vptr + VSTRIDE, &V_lds[cur ^ 1][kdst]);
    }
    kptr += KSTRIDE;
    vptr += VSTRIDE;
    if (kv0 <= q0w + 15) {  // wave-uniform: skip tiles fully above the diagonal
      const char* Kb = (const char*)K_lds[cur];
      const char* Vb = (const char*)V_lds[cur];
      // ---- S^T = mfma(K, Q): s[nk][r] = S[q=qg][kv = kv0 + 16nk + 4g + r]
      f32x4 s[4] = {};
      #pragma unroll
      for (int ks = 0; ks < 2; ++ks) {
        bf16x8 kf[4];
        #pragma unroll
        for (int nk = 0; nk < 4; ++nk) {
          int row = nk * 16 + c;
          kf[nk] = *(const bf16x8*)(Kb + row * 128 + ((ks * 64 + g * 16) ^ ((row & 7) << 4)));
        }
        __builtin_amdgcn_s_setprio(1);
        #pragma unroll
        for (int nk = 0; nk < 4; ++nk)
          s[nk] = __builtin_amdgcn_mfma_f32_16x16x32_bf16(kf[nk], qf[ks], s[nk], 0, 0, 0);
        __builtin_amdgcn_s_setprio(0);
      }
      // ---- causal mask on any tile straddling this wave's rows (wave-uniform)
      if (kv0 + 63 > q0w) {
        #pragma unroll
        for (int nk = 0; nk < 4; ++nk)
          #pragma unroll
          for (int r = 0; r < 4; ++r) {
            int kvg = kv0 + nk * 16 + 4 * g + r;
            if (kvg > qg) s[nk][r] = -1e30f;
          }
      }
      // ---- row max: in-lane tree + 2 shfls (lanes c,c+16,c+32,c+48 share q)
      float a0 = fmaxf(fmaxf(s[0][0], s[0][1]), fmaxf(s[0][2], s[0][3]));
      float a1 = fmaxf(fmaxf(s[1][0], s[1][1]), fmaxf(s[1][2], s[1][3]));
      float a2 = fmaxf(fmaxf(s[2][0], s[2][1]), fmaxf(s[2][2], s[2][3]));
      float a3 = fmaxf(fmaxf(s[3][0], s[3][1]), fmaxf(s[3][2], s[3][3]));
      float mx = fmaxf(fmaxf(a0, a1), fmaxf(a2, a3));
      mx = fmaxf(mx, __shfl_xor(mx, 16));
      mx = fmaxf(mx, __shfl_xor(mx, 32));
      // ---- alpha==1 fast path (wave-uniform); rescale lane-local
      if (!__all(mx <= mstate)) {
        float mnew = fmaxf(mstate, mx);
        float alpha = exp2f((mstate - mnew) * SCL);
        mstate = mnew;
        lstate *= alpha;
        #pragma unroll
        for (int nd = 0; nd < 4; ++nd) acc[nd] *= alpha;
      }
      // ---- P = exp2(s*SCL - m*SCL), per-lane l partial
      float ms = mstate * SCL;
      #pragma unroll
      for (int nk = 0; nk < 4; ++nk) {
        #pragma unroll
        for (int r = 0; r < 4; ++r) s[nk][r] = exp2f(fmaf(s[nk][r], SCL, -ms));
        lstate += (s[nk][0] + s[nk][1]) + (s[nk][2] + s[nk][3]);
      }
      // ---- pack P to bf16 pairs
      unsigned pk[4][2];
      #pragma unroll
      for (int nk = 0; nk < 4; ++nk) {
        pk[nk][0] = cvtpk_bf16(s[nk][0], s[nk][1]);
        pk[nk][1] = cvtpk_bf16(s[nk][2], s[nk][3]);
      }
      // ---- O^T += mfma(V^T, P^T): B-frag pa[vks] = P[q=c][kv=32vks+8g+e]
      #pragma unroll
      for (int vks = 0; vks < 2; ++vks) {
        unsigned rA00 = __shfl(pk[2 * vks][0], srcA, 64);
        unsigned rA01 = __shfl(pk[2 * vks][1], srcA, 64);
        unsigned rA10 = __shfl(pk[2 * vks + 1][0], srcA, 64);
        unsigned rA11 = __shfl(pk[2 * vks + 1][1], srcA, 64);
        unsigned rB00 = __shfl(pk[2 * vks][0], srcB, 64);
        unsigned rB01 = __shfl(pk[2 * vks][1], srcB, 64);
        unsigned rB10 = __shfl(pk[2 * vks + 1][0], srcB, 64);
        unsigned rB11 = __shfl(pk[2 * vks + 1][1], srcB, 64);
        union { unsigned u[4]; bf16x8 v; } pa;
        pa.u[0] = hi ? rA10 : rA00;
        pa.u[1] = hi ? rA11 : rA01;
        pa.u[2] = hi ? rB10 : rB00;
        pa.u[3] = hi ? rB11 : rB01;
        bf16x8 vf[4];
        #pragma unroll
        for (int nd = 0; nd < 4; ++nd) {
          int row = nd * 16 + c;
          vf[nd] = *(const bf16x8*)(Vb + row * 128 + ((vks * 64 + g * 16) ^ ((row & 7) << 4)));
        }
        __builtin_amdgcn_s_setprio(1);
        #pragma unroll
        for (int nd = 0; nd < 4; ++nd)
          acc[nd] = __builtin_amdgcn_mfma_f32_16x16x32_bf16(vf[nd], pa.v, acc[nd], 0, 0, 0);
        __builtin_amdgcn_s_setprio(0);
      }
    }
    __syncthreads();  // one barrier per tile (drains both async gloads)
  }

  // ---- epilogue: reduce l over the 4 g-lanes sharing q=c; write partials
  float lsum = lstate;
  lsum += __shfl_xor(lsum, 16);
  lsum += __shfl_xor(lsum, 32);
  const int qrow = w * 16 + c;                     // 0..127 within q-tile
  #pragma unroll
  for (int nd = 0; nd < 4; ++nd) {
    ushort4 o4;
    o4.x = f2b(acc[nd][0]); o4.y = f2b(acc[nd][1]);
    o4.z = f2b(acc[nd][2]); o4.w = f2b(acc[nd][3]);
    *(ushort4*)(partO + (size_t)bid * 8192 + qrow * 64 + nd * 16 + 4 * g) = o4;
  }
  if (g == 0) {
    partML[(size_t)bid * 256 + qrow * 2 + 0] = mstate;
    partML[(size_t)bid * 256 + qrow * 2 + 1] = lsum;
  }
}

// ---------------- combine: merge <=4 KV-chunk partials per 128-row q-tile ----
__global__ __launch_bounds__(256) void attn_combine(const unsigned short* __restrict__ partO,
                                                    const float* __restrict__ partML,
                                                    unsigned short* __restrict__ out) {
  const int bid = blockIdx.x;                      // 512 = 16 qt x 32 bh
  const int qt = bid >> 5, bh = bid & 31;
  const int b = bh >> 4, h = bh & 15;
  const int np = (2 * qt + 9) >> 3;                // ceil((2qt+2)/8)
  const int base = (qt < 4) ? qt
                 : (qt < 8) ? 4 + 2 * (qt - 4)
                 : (qt < 12) ? 12 + 3 * (qt - 8)
                 : 24 + 4 * (qt - 12);
  const int t = threadIdx.x;
  const int row = t >> 1, cg = (t & 1) * 32;       // 128 rows x 2 col-halves of 32
  const float SCL = 0.18033688f;
  // attn dispatches chunk cid_work at raw bid-chunk (39 - cid_work)
  float mstar = -1e30f;
  #pragma unroll
  for (int p = 0; p < 4; ++p)
    if (p < np)
      mstar = fmaxf(mstar, partML[(size_t)(((39 - (base + p)) << 5) | bh) * 256 + row * 2]);
  float L = 0.f;
  float o[32];
  #pragma unroll
  for (int j = 0; j < 32; ++j) o[j] = 0.f;
  #pragma unroll
  for (int p = 0; p < 4; ++p) {
    if (p < np) {
      int slot = ((39 - (base + p)) << 5) | bh;
      float mp = partML[(size_t)slot * 256 + row * 2 + 0];
      float lp = partML[(size_t)slot * 256 + row * 2 + 1];
      float wgt = exp2f((mp - mstar) * SCL);
      L = fmaf(wgt, lp, L);
      const unsigned short* src = partO + (size_t)slot * 8192 + row * 64 + cg;
      #pragma unroll
      for (int q = 0; q < 4; ++q) {
        u16x8 a = *(const u16x8*)(src + q * 8);
        #pragma unroll
        for (int j = 0; j < 8; ++j)
          o[q * 8 + j] = fmaf(b2f(a[j]), wgt, o[q * 8 + j]);
      }
    }
  }
  float rinv = 1.0f / L;
  size_t trow = (size_t)b * 2048 + qt * 128 + row;
  #pragma unroll
  for (int q = 0; q < 4; ++q) {
    u16x8 r;
    #pragma unroll
    for (int j = 0; j < 8; ++j) r[j] = f2b(o[q * 8 + j] * rinv);
    *(u16x8*)(out + trow * 1024 + h * 64 + cg + q * 8) = r;
  }
}

// ---------------- launch ----------------
extern "C" void kernel_launch(void* const* d_in, const int* in_sizes, int n_in,
                              void* d_out, int out_size, void* d_ws, size_t ws_size,
                              hipStream_t stream) {
  const float* x      = (const float*)d_in[0];
  const float* W_attn = (const float*)d_in[1];
  const float* b_attn = (const float*)d_in[2];
  const float* W_proj = (const float*)d_in[3];
  const float* b_proj = (const float*)d_in[4];
  float* out = (float*)d_out;

  char* ws = (char*)d_ws;
  // layout (57.9 MB total):
  //   Wproj_t  [0,        2097152)
  //   qk       [2097152,  18874368)  [4096][2048] bf16 (Q,K)
  //   vT       [18874368, 27262976)  [1024][4096] bf16 (V^T)
  //   x_bf     [27262976, 35651584)  dead after GEMM1 \ overlapped by partO
  //   Wattn_t  [35651584, 41943040)  dead after GEMM1 /
  //   partO    [27262976, 48234496)
  //   attn_out [48234496, 56623104)
  //   partML   [56623104, 57933824)
  unsigned short* Wproj_t  = (unsigned short*)(ws + 0);
  unsigned short* qk       = (unsigned short*)(ws + 2097152);
  unsigned short* vT       = (unsigned short*)(ws + 18874368);
  unsigned short* x_bf     = (unsigned short*)(ws + 27262976);
  unsigned short* Wattn_t  = (unsigned short*)(ws + 35651584);
  unsigned short* partO    = (unsigned short*)(ws + 27262976);
  unsigned short* attn_out = (unsigned short*)(ws + 48234496);
  float*          partML   = (float*)(ws + 56623104);

  convert_f32_bf16<<<2048, 256, 0, stream>>>(x, x_bf, 4194304);
  transpose_f32_bf16<<<dim3(96, 32), dim3(32, 8), 0, stream>>>(W_attn, Wattn_t, 1024, 3072);
  transpose_f32_bf16<<<dim3(32, 32), dim3(32, 8), 0, stream>>>(W_proj, Wproj_t, 1024, 1024);

  gemm_bt<true, true><<<dim3(32, 24), 256, 0, stream>>>(x_bf, Wattn_t, b_attn, qk, vT,
                                                        4096, 3072, 1024);
  attn_kernel<<<1280, 512, 0, stream>>>(qk, vT, partO, partML);
  attn_combine<<<512, 256, 0, stream>>>(partO, partML, attn_out);
  gemm_bt<false, false><<<dim3(32, 8), 256, 0, stream>>>(attn_out, Wproj_t, b_proj, out, nullptr,
                                                         4096, 1024, 1024);
}

// Round 14
// 137.115 us; speedup vs baseline: 1.6963x; 1.0822x over previous
//
#include <hip/hip_runtime.h>
#include <stdint.h>

typedef __attribute__((ext_vector_type(4))) float f32x4;
typedef __attribute__((ext_vector_type(8))) __bf16 bf16x8;
typedef __attribute__((ext_vector_type(8))) unsigned short u16x8;

__device__ __forceinline__ unsigned short f2b(float f) {
  unsigned u = __float_as_uint(f);
  u += 0x7FFFu + ((u >> 16) & 1u);   // RNE
  return (unsigned short)(u >> 16);
}
__device__ __forceinline__ float b2f(unsigned short s) {
  unsigned u = (unsigned)s << 16;
  return __uint_as_float(u);
}
__device__ __forceinline__ unsigned cvtpk_bf16(float lo, float hi) {
  unsigned r;
  asm("v_cvt_pk_bf16_f32 %0, %1, %2" : "=v"(r) : "v"(lo), "v"(hi));
  return r;
}

__device__ __forceinline__ void gload_lds16(const void* g, void* l) {
  typedef __attribute__((address_space(1))) void GV1;
  typedef __attribute__((address_space(3))) void LV3;
  __builtin_amdgcn_global_load_lds((GV1*)(void*)g, (LV3*)l, 16, 0, 0);
}

// ---------------- conversion kernels ----------------
__global__ __launch_bounds__(256) void convert_f32_bf16(const float* __restrict__ in,
                                                        unsigned short* __restrict__ out, int n) {
  int i = (blockIdx.x * 256 + threadIdx.x) * 8;
  if (i >= n) return;
  float4 a = *(const float4*)(in + i);
  float4 b = *(const float4*)(in + i + 4);
  u16x8 r;
  r[0] = f2b(a.x); r[1] = f2b(a.y); r[2] = f2b(a.z); r[3] = f2b(a.w);
  r[4] = f2b(b.x); r[5] = f2b(b.y); r[6] = f2b(b.z); r[7] = f2b(b.w);
  *(u16x8*)(out + i) = r;
}

// W [K][N] f32 -> Wt [N][K] bf16
__global__ __launch_bounds__(256) void transpose_f32_bf16(const float* __restrict__ W,
                                                          unsigned short* __restrict__ Wt,
                                                          int K, int N) {
  __shared__ unsigned short tile[32][33];
  int n0 = blockIdx.x * 32, k0 = blockIdx.y * 32;
  int tx = threadIdx.x, ty = threadIdx.y;  // 32 x 8
  #pragma unroll
  for (int j = 0; j < 32; j += 8)
    tile[ty + j][tx] = f2b(W[(size_t)(k0 + ty + j) * N + n0 + tx]);
  __syncthreads();
  #pragma unroll
  for (int j = 0; j < 32; j += 8)
    Wt[(size_t)(n0 + ty + j) * K + k0 + tx] = tile[tx][ty + j];
}

// ---------------- GEMM: C[M][N] = A[M][K] * Bt[N][K]^T + bias ----------------
// R13: 2-PHASE DOUBLE-BUFFER (attn-proven): issue next K-step's global_load_lds
// BEFORE compute, one barrier per step (was: stage/barrier/compute/barrier).
// 8 waves (512 thr), wave-tile 64x32 (acc[4][2]) -> lower VGPR, 16 waves/CU at
// the 64KB LDS (2 blocks/CU). VSPLIT epilogue transposes V via LDS (stride 136,
// reusing the dead 64KB staging buffer) for coalesced vT writes.
template <bool OUT_BF16, bool VSPLIT>
__global__ __launch_bounds__(512) void gemm_bt(const unsigned short* __restrict__ A,
                                               const unsigned short* __restrict__ Bt,
                                               const float* __restrict__ bias,
                                               void* __restrict__ Cout,
                                               unsigned short* __restrict__ vT,
                                               int M, int N, int K) {
  __shared__ unsigned short SMEM[32768];           // 64KB: [buf][A|B][128*64]
  const int m0 = blockIdx.x * 128, n0 = blockIdx.y * 128;
  const int tid = threadIdx.x;
  const int w = tid >> 6, l = tid & 63;
  const int wm = w >> 2, wn = w & 3;               // 2 x 4 waves, tile 64 x 32
  const int c = l & 15, g = l >> 4;
  const int NT = K >> 6;                           // K-steps (BK=64)
  // hoisted per-lane staging pointers (advance by 64 per step)
  const unsigned short* aptr[2];
  const unsigned short* bptr[2];
  #pragma unroll
  for (int i = 0; i < 2; ++i) {
    int rb = w * 16 + i * 8;
    aptr[i] = A  + (size_t)(m0 + rb + (l >> 3)) * K + (l & 7) * 8;
    bptr[i] = Bt + (size_t)(n0 + rb + (l >> 3)) * K + (l & 7) * 8;
  }
  f32x4 acc[4][2] = {};
  // ---- prologue: stage step 0 into buf 0
  #pragma unroll
  for (int i = 0; i < 2; ++i) {
    int rb = w * 16 + i * 8;
    gload_lds16(aptr[i], &SMEM[rb * 64]);
    gload_lds16(bptr[i], &SMEM[8192 + rb * 64]);
  }
  __syncthreads();
  for (int t = 0; t < NT; ++t) {
    const int cur = t & 1;
    const unsigned short* Ab = &SMEM[cur * 16384];
    const unsigned short* Bb = &SMEM[cur * 16384 + 8192];
    if (t + 1 < NT) {  // issue next-step loads BEFORE compute (2-phase)
      unsigned short* An = &SMEM[(cur ^ 1) * 16384];
      unsigned short* Bn = &SMEM[(cur ^ 1) * 16384 + 8192];
      #pragma unroll
      for (int i = 0; i < 2; ++i) {
        int rb = w * 16 + i * 8;
        gload_lds16(aptr[i] + (size_t)(t + 1) * 64, &An[rb * 64]);
        gload_lds16(bptr[i] + (size_t)(t + 1) * 64, &Bn[rb * 64]);
      }
    }
    #pragma unroll
    for (int ks = 0; ks < 2; ++ks) {
      bf16x8 af[4], bf[2];
      #pragma unroll
      for (int mi = 0; mi < 4; ++mi)
        af[mi] = *(const bf16x8*)&Ab[(wm * 64 + mi * 16 + c) * 64 + ks * 32 + g * 8];
      #pragma unroll
      for (int ni = 0; ni < 2; ++ni)
        bf[ni] = *(const bf16x8*)&Bb[(wn * 32 + ni * 16 + c) * 64 + ks * 32 + g * 8];
      __builtin_amdgcn_s_setprio(1);
      #pragma unroll
      for (int mi = 0; mi < 4; ++mi)
        #pragma unroll
        for (int ni = 0; ni < 2; ++ni)
          acc[mi][ni] = __builtin_amdgcn_mfma_f32_16x16x32_bf16(af[mi], bf[ni], acc[mi][ni], 0, 0, 0);
      __builtin_amdgcn_s_setprio(0);
    }
    __syncthreads();  // one barrier per step
  }
  if (VSPLIT && n0 >= 2048) {
    // ---- V block: transpose via LDS (dead staging buffer), coalesced vT write
    unsigned short* TR = SMEM;                     // [128 cols][136] (17408 elems)
    #pragma unroll
    for (int mi = 0; mi < 4; ++mi)
      #pragma unroll
      for (int ni = 0; ni < 2; ++ni) {
        int cl = wn * 32 + ni * 16 + c;
        float bv = bias[n0 + cl];
        int rlb = wm * 64 + mi * 16 + 4 * g;
        ushort4 o4;
        o4.x = f2b(acc[mi][ni][0] + bv); o4.y = f2b(acc[mi][ni][1] + bv);
        o4.z = f2b(acc[mi][ni][2] + bv); o4.w = f2b(acc[mi][ni][3] + bv);
        *(ushort4*)&TR[cl * 136 + rlb] = o4;
      }
    __syncthreads();
    const int d0 = n0 - 2048;
    #pragma unroll
    for (int p = 0; p < 4; ++p) {
      int rowl = p * 32 + (tid >> 4);
      *(u16x8*)(vT + (size_t)(d0 + rowl) * 4096 + m0 + (tid & 15) * 8) =
          *(const u16x8*)&TR[rowl * 136 + (tid & 15) * 8];
    }
    return;
  }
  const int NS = VSPLIT ? 2048 : N;                // qk buffer stride for VSPLIT
  #pragma unroll
  for (int mi = 0; mi < 4; ++mi) {
    #pragma unroll
    for (int ni = 0; ni < 2; ++ni) {
      int colg = n0 + wn * 32 + ni * 16 + c;
      float bv = bias[colg];
      #pragma unroll
      for (int r = 0; r < 4; ++r) {
        int rowg = m0 + wm * 64 + mi * 16 + 4 * g + r;
        float v = acc[mi][ni][r] + bv;
        if (OUT_BF16)
          ((unsigned short*)Cout)[(size_t)rowg * NS + colg] = f2b(v);
        else
          ((float*)Cout)[(size_t)rowg * NS + colg] = v;
      }
    }
  }
}

// ---------------- causal flash attention, SPLIT-KV + SWAPPED MFMA, QBLK=128 ----
// (unchanged from R13 — at its ~62us structural floor)
__global__ __launch_bounds__(512) void attn_kernel(const unsigned short* __restrict__ qk,
                                                   const unsigned short* __restrict__ vT,
                                                   unsigned short* __restrict__ partO,
                                                   float* __restrict__ partML) {
  __shared__ unsigned short K_lds[2][64 * 64];     // [kv][d], XOR-swizzled rows
  __shared__ unsigned short V_lds[2][64 * 64];     // V^T [d][kv], XOR-swizzled rows
  const int bid = blockIdx.x;
  const int bh = bid & 31;
  const int cid = 39 - (bid >> 5);                 // heavy-first
  int qt, ct;
  if (cid < 4)       { qt = cid;            ct = 0; }
  else if (cid < 12) { int e = cid - 4;  qt = 4 + (e >> 1);  ct = e & 1; }
  else if (cid < 24) { int e = cid - 12; int q3 = e / 3; qt = 8 + q3; ct = e - 3 * q3; }
  else               { int e = cid - 24; qt = 12 + (e >> 2); ct = e & 3; }
  const int ntt = 2 * qt + 2;                      // total kv tiles for this q-tile
  const int t0 = ct * 8;
  const int ntl = min(ntt - t0, 8);                // tiles in this chunk (1..8)
  const int b = bh >> 4, h = bh & 15;
  const int tid = threadIdx.x, w = tid >> 6, l = tid & 63;
  const int c = l & 15, g = l >> 4;
  const int hi = g >> 1;
  const int srcA = c + ((g & 1) << 5);             // bpermute pattern A (j=0,1)
  const int srcB = srcA + 16;                      // pattern B (j=2,3)
  const size_t row0 = (size_t)b * 2048;
  const float SCL = 0.18033688f;                   // 0.125 * log2(e)
  const int KSTRIDE = 64 * 2048;                   // qk elems per kv-tile step
  const int VSTRIDE = 64;                          // vT elems per kv-tile step

  const int q0w = qt * 128 + w * 16;
  const int qg = q0w + c;                          // this lane's q row (global)

  // Q fragments (B operand of swapped QK^T)
  bf16x8 qf[2];
  #pragma unroll
  for (int ks = 0; ks < 2; ++ks)
    qf[ks] = *(const bf16x8*)(qk + (row0 + qg) * 2048 + h * 64 + ks * 32 + g * 8);

  f32x4 acc[4] = {};                               // O^T: acc[nd][r] = O[q=c][d=16nd+4g+r]
  float mstate = -1e30f, lstate = 0.f;

  // ---- hoisted per-lane global pointers (advance per tile)
  const int krow = w * 8 + (l >> 3);               // lane's row in tile (K: kv; V: d)
  const int kch = (l & 7) ^ (krow & 7);            // pre-swizzled source chunk (m173)
  const unsigned short* kptr = qk + (row0 + t0 * 64 + krow) * 2048 + 1024 + h * 64 + kch * 8;
  const unsigned short* vptr = vT + (size_t)(h * 64 + krow) * 4096 + (b * 2048 + t0 * 64) + kch * 8;
  const int kdst = (w * 8) * 64;                   // wave-uniform LDS base (elems)

  // ---- prologue: stage kv-tile t0 into buffer 0 (both fully async)
  gload_lds16(kptr, &K_lds[0][kdst]);
  gload_lds16(vptr, &V_lds[0][kdst]);
  __syncthreads();

  for (int lt = 0; lt < ntl; ++lt) {
    const int cur = lt & 1;
    const int kv0 = (t0 + lt) * 64;
    const bool pre = (lt + 1 < ntl);
    if (pre) {  // issue next-tile async loads BEFORE compute (2-phase pipeline)
      gload_lds16(kptr + KSTRIDE, &K_lds[cur ^ 1][kdst]);
      gload_lds16(vptr + VSTRIDE, &V_lds[cur ^ 1][kdst]);
    }
    kptr += KSTRIDE;
    vptr += VSTRIDE;
    if (kv0 <= q0w + 15) {  // wave-uniform: skip tiles fully above the diagonal
      const char* Kb = (const char*)K_lds[cur];
      const char* Vb = (const char*)V_lds[cur];
      // ---- S^T = mfma(K, Q): s[nk][r] = S[q=qg][kv = kv0 + 16nk + 4g + r]
      f32x4 s[4] = {};
      #pragma unroll
      for (int ks = 0; ks < 2; ++ks) {
        bf16x8 kf[4];
        #pragma unroll
        for (int nk = 0; nk < 4; ++nk) {
          int row = nk * 16 + c;
          kf[nk] = *(const bf16x8*)(Kb + row * 128 + ((ks * 64 + g * 16) ^ ((row & 7) << 4)));
        }
        __builtin_amdgcn_s_setprio(1);
        #pragma unroll
        for (int nk = 0; nk < 4; ++nk)
          s[nk] = __builtin_amdgcn_mfma_f32_16x16x32_bf16(kf[nk], qf[ks], s[nk], 0, 0, 0);
        __builtin_amdgcn_s_setprio(0);
      }
      // ---- causal mask on any tile straddling this wave's rows (wave-uniform)
      if (kv0 + 63 > q0w) {
        #pragma unroll
        for (int nk = 0; nk < 4; ++nk)
          #pragma unroll
          for (int r = 0; r < 4; ++r) {
            int kvg = kv0 + nk * 16 + 4 * g + r;
            if (kvg > qg) s[nk][r] = -1e30f;
          }
      }
      // ---- row max: in-lane tree + 2 shfls (lanes c,c+16,c+32,c+48 share q)
      float a0 = fmaxf(fmaxf(s[0][0], s[0][1]), fmaxf(s[0][2], s[0][3]));
      float a1 = fmaxf(fmaxf(s[1][0], s[1][1]), fmaxf(s[1][2], s[1][3]));
      float a2 = fmaxf(fmaxf(s[2][0], s[2][1]), fmaxf(s[2][2], s[2][3]));
      float a3 = fmaxf(fmaxf(s[3][0], s[3][1]), fmaxf(s[3][2], s[3][3]));
      float mx = fmaxf(fmaxf(a0, a1), fmaxf(a2, a3));
      mx = fmaxf(mx, __shfl_xor(mx, 16));
      mx = fmaxf(mx, __shfl_xor(mx, 32));
      // ---- alpha==1 fast path (wave-uniform); rescale lane-local
      if (!__all(mx <= mstate)) {
        float mnew = fmaxf(mstate, mx);
        float alpha = exp2f((mstate - mnew) * SCL);
        mstate = mnew;
        lstate *= alpha;
        #pragma unroll
        for (int nd = 0; nd < 4; ++nd) acc[nd] *= alpha;
      }
      // ---- P = exp2(s*SCL - m*SCL), per-lane l partial
      float ms = mstate * SCL;
      #pragma unroll
      for (int nk = 0; nk < 4; ++nk) {
        #pragma unroll
        for (int r = 0; r < 4; ++r) s[nk][r] = exp2f(fmaf(s[nk][r], SCL, -ms));
        lstate += (s[nk][0] + s[nk][1]) + (s[nk][2] + s[nk][3]);
      }
      // ---- pack P to bf16 pairs
      unsigned pk[4][2];
      #pragma unroll
      for (int nk = 0; nk < 4; ++nk) {
        pk[nk][0] = cvtpk_bf16(s[nk][0], s[nk][1]);
        pk[nk][1] = cvtpk_bf16(s[nk][2], s[nk][3]);
      }
      // ---- O^T += mfma(V^T, P^T): B-frag pa[vks] = P[q=c][kv=32vks+8g+e]
      #pragma unroll
      for (int vks = 0; vks < 2; ++vks) {
        unsigned rA00 = __shfl(pk[2 * vks][0], srcA, 64);
        unsigned rA01 = __shfl(pk[2 * vks][1], srcA, 64);
        unsigned rA10 = __shfl(pk[2 * vks + 1][0], srcA, 64);
        unsigned rA11 = __shfl(pk[2 * vks + 1][1], srcA, 64);
        unsigned rB00 = __shfl(pk[2 * vks][0], srcB, 64);
        unsigned rB01 = __shfl(pk[2 * vks][1], srcB, 64);
        unsigned rB10 = __shfl(pk[2 * vks + 1][0], srcB, 64);
        unsigned rB11 = __shfl(pk[2 * vks + 1][1], srcB, 64);
        union { unsigned u[4]; bf16x8 v; } pa;
        pa.u[0] = hi ? rA10 : rA00;
        pa.u[1] = hi ? rA11 : rA01;
        pa.u[2] = hi ? rB10 : rB00;
        pa.u[3] = hi ? rB11 : rB01;
        bf16x8 vf[4];
        #pragma unroll
        for (int nd = 0; nd < 4; ++nd) {
          int row = nd * 16 + c;
          vf[nd] = *(const bf16x8*)(Vb + row * 128 + ((vks * 64 + g * 16) ^ ((row & 7) << 4)));
        }
        __builtin_amdgcn_s_setprio(1);
        #pragma unroll
        for (int nd = 0; nd < 4; ++nd)
          acc[nd] = __builtin_amdgcn_mfma_f32_16x16x32_bf16(vf[nd], pa.v, acc[nd], 0, 0, 0);
        __builtin_amdgcn_s_setprio(0);
      }
    }
    __syncthreads();  // one barrier per tile (drains both async gloads)
  }

  // ---- epilogue: reduce l over the 4 g-lanes sharing q=c; write partials
  float lsum = lstate;
  lsum += __shfl_xor(lsum, 16);
  lsum += __shfl_xor(lsum, 32);
  const int qrow = w * 16 + c;                     // 0..127 within q-tile
  #pragma unroll
  for (int nd = 0; nd < 4; ++nd) {
    ushort4 o4;
    o4.x = f2b(acc[nd][0]); o4.y = f2b(acc[nd][1]);
    o4.z = f2b(acc[nd][2]); o4.w = f2b(acc[nd][3]);
    *(ushort4*)(partO + (size_t)bid * 8192 + qrow * 64 + nd * 16 + 4 * g) = o4;
  }
  if (g == 0) {
    partML[(size_t)bid * 256 + qrow * 2 + 0] = mstate;
    partML[(size_t)bid * 256 + qrow * 2 + 1] = lsum;
  }
}

// ---------------- combine: merge <=4 KV-chunk partials per 128-row q-tile ----
__global__ __launch_bounds__(256) void attn_combine(const unsigned short* __restrict__ partO,
                                                    const float* __restrict__ partML,
                                                    unsigned short* __restrict__ out) {
  const int bid = blockIdx.x;                      // 512 = 16 qt x 32 bh
  const int qt = bid >> 5, bh = bid & 31;
  const int b = bh >> 4, h = bh & 15;
  const int np = (2 * qt + 9) >> 3;                // ceil((2qt+2)/8)
  const int base = (qt < 4) ? qt
                 : (qt < 8) ? 4 + 2 * (qt - 4)
                 : (qt < 12) ? 12 + 3 * (qt - 8)
                 : 24 + 4 * (qt - 12);
  const int t = threadIdx.x;
  const int row = t >> 1, cg = (t & 1) * 32;       // 128 rows x 2 col-halves of 32
  const float SCL = 0.18033688f;
  // attn dispatches chunk cid_work at raw bid-chunk (39 - cid_work)
  float mstar = -1e30f;
  #pragma unroll
  for (int p = 0; p < 4; ++p)
    if (p < np)
      mstar = fmaxf(mstar, partML[(size_t)(((39 - (base + p)) << 5) | bh) * 256 + row * 2]);
  float L = 0.f;
  float o[32];
  #pragma unroll
  for (int j = 0; j < 32; ++j) o[j] = 0.f;
  #pragma unroll
  for (int p = 0; p < 4; ++p) {
    if (p < np) {
      int slot = ((39 - (base + p)) << 5) | bh;
      float mp = partML[(size_t)slot * 256 + row * 2 + 0];
      float lp = partML[(size_t)slot * 256 + row * 2 + 1];
      float wgt = exp2f((mp - mstar) * SCL);
      L = fmaf(wgt, lp, L);
      const unsigned short* src = partO + (size_t)slot * 8192 + row * 64 + cg;
      #pragma unroll
      for (int q = 0; q < 4; ++q) {
        u16x8 a = *(const u16x8*)(src + q * 8);
        #pragma unroll
        for (int j = 0; j < 8; ++j)
          o[q * 8 + j] = fmaf(b2f(a[j]), wgt, o[q * 8 + j]);
      }
    }
  }
  float rinv = 1.0f / L;
  size_t trow = (size_t)b * 2048 + qt * 128 + row;
  #pragma unroll
  for (int q = 0; q < 4; ++q) {
    u16x8 r;
    #pragma unroll
    for (int j = 0; j < 8; ++j) r[j] = f2b(o[q * 8 + j] * rinv);
    *(u16x8*)(out + trow * 1024 + h * 64 + cg + q * 8) = r;
  }
}

// ---------------- launch ----------------
extern "C" void kernel_launch(void* const* d_in, const int* in_sizes, int n_in,
                              void* d_out, int out_size, void* d_ws, size_t ws_size,
                              hipStream_t stream) {
  const float* x      = (const float*)d_in[0];
  const float* W_attn = (const float*)d_in[1];
  const float* b_attn = (const float*)d_in[2];
  const float* W_proj = (const float*)d_in[3];
  const float* b_proj = (const float*)d_in[4];
  float* out = (float*)d_out;

  char* ws = (char*)d_ws;
  // layout (57.9 MB total):
  //   Wproj_t  [0,        2097152)
  //   qk       [2097152,  18874368)  [4096][2048] bf16 (Q,K)
  //   vT       [18874368, 27262976)  [1024][4096] bf16 (V^T)
  //   x_bf     [27262976, 35651584)  dead after GEMM1 \ overlapped by partO
  //   Wattn_t  [35651584, 41943040)  dead after GEMM1 /
  //   partO    [27262976, 48234496)
  //   attn_out [48234496, 56623104)
  //   partML   [56623104, 57933824)
  unsigned short* Wproj_t  = (unsigned short*)(ws + 0);
  unsigned short* qk       = (unsigned short*)(ws + 2097152);
  unsigned short* vT       = (unsigned short*)(ws + 18874368);
  unsigned short* x_bf     = (unsigned short*)(ws + 27262976);
  unsigned short* Wattn_t  = (unsigned short*)(ws + 35651584);
  unsigned short* partO    = (unsigned short*)(ws + 27262976);
  unsigned short* attn_out = (unsigned short*)(ws + 48234496);
  float*          partML   = (float*)(ws + 56623104);

  convert_f32_bf16<<<2048, 256, 0, stream>>>(x, x_bf, 4194304);
  transpose_f32_bf16<<<dim3(96, 32), dim3(32, 8), 0, stream>>>(W_attn, Wattn_t, 1024, 3072);
  transpose_f32_bf16<<<dim3(32, 32), dim3(32, 8), 0, stream>>>(W_proj, Wproj_t, 1024, 1024);

  gemm_bt<true, true><<<dim3(32, 24), 512, 0, stream>>>(x_bf, Wattn_t, b_attn, qk, vT,
                                                        4096, 3072, 1024);
  attn_kernel<<<1280, 512, 0, stream>>>(qk, vT, partO, partML);
  attn_combine<<<512, 256, 0, stream>>>(partO, partML, attn_out);
  gemm_bt<false, false><<<dim3(32, 8), 512, 0, stream>>>(attn_out, Wproj_t, b_proj, out, nullptr,
                                                         4096, 1024, 1024);
}